// Round 1
// baseline (1159.966 us; speedup 1.0000x reference)
//
#include <hip/hip_runtime.h>
#include <math.h>

#define BB 4
#define LL 2048
#define DD 512
#define EPSF 1e-5f

// ---------------------------------------------------------------------------
// K1: x_act = tanh(x), and kk[row] = sum(x_act^2) per (b,l) row.
// One wave per row (512 elems = 64 lanes x 8). 4 rows per 256-thread WG.
// ---------------------------------------------------------------------------
__global__ __launch_bounds__(256) void k_tanh(const float* __restrict__ x,
                                              float* __restrict__ xa,
                                              float* __restrict__ kk) {
  int row  = blockIdx.x * 4 + (threadIdx.x >> 6);   // [0, 8192)
  int lane = threadIdx.x & 63;
  const float* xr = x + (size_t)row * DD + lane * 8;
  float4 a = *(const float4*)xr;
  float4 b = *(const float4*)(xr + 4);
  float v[8] = {a.x, a.y, a.z, a.w, b.x, b.y, b.z, b.w};
  float ss = 0.f;
#pragma unroll
  for (int j = 0; j < 8; ++j) {
    v[j] = tanhf(v[j]);
    ss = fmaf(v[j], v[j], ss);
  }
  float4 o0 = {v[0], v[1], v[2], v[3]};
  float4 o1 = {v[4], v[5], v[6], v[7]};
  float* xar = xa + (size_t)row * DD + lane * 8;
  *(float4*)xar = o0;
  *(float4*)(xar + 4) = o1;
#pragma unroll
  for (int m = 1; m < 64; m <<= 1) ss += __shfl_xor(ss, m, 64);
  if (lane == 0) kk[row] = ss;
}

// ---------------------------------------------------------------------------
// K2: static_out = x_act @ W^T.  C[m,e] = sum_d A[m,d]*W[e,d].
// fp32 tiled: 128x64 tile per 256-thread WG, 8x4 micro-tile per thread.
// LDS tiles stored K-major so compute reads are b128 + broadcast-friendly.
// ---------------------------------------------------------------------------
#define TM 128
#define TN 64
#define TK 32
__global__ __launch_bounds__(256) void k_gemm(const float* __restrict__ A,
                                              const float* __restrict__ W,
                                              float* __restrict__ C) {
  __shared__ float As[TK][TM];  // 16 KB
  __shared__ float Bs[TK][TN];  // 8 KB
  int tid = threadIdx.x;
  int m0 = blockIdx.x * TM;
  int e0 = blockIdx.y * TN;
  int r0 = (tid >> 4) * 8;   // [0,128) step 8
  int c0 = (tid & 15) * 4;   // [0,64)  step 4
  float acc[8][4] = {};
  for (int k0 = 0; k0 < DD; k0 += TK) {
    // A tile: 128 rows x 32 k, transposed into As[k][m]
#pragma unroll
    for (int i = 0; i < 4; ++i) {
      int idx = tid + i * 256;
      int amr = idx >> 3, amc = idx & 7;
      float4 v = *(const float4*)(A + (size_t)(m0 + amr) * DD + k0 + amc * 4);
      As[amc * 4 + 0][amr] = v.x;
      As[amc * 4 + 1][amr] = v.y;
      As[amc * 4 + 2][amr] = v.z;
      As[amc * 4 + 3][amr] = v.w;
    }
    // W tile: 64 rows(e) x 32 k, transposed into Bs[k][e]
#pragma unroll
    for (int i = 0; i < 2; ++i) {
      int idx = tid + i * 256;
      int br = idx >> 3, bc = idx & 7;
      float4 v = *(const float4*)(W + (size_t)(e0 + br) * DD + k0 + bc * 4);
      Bs[bc * 4 + 0][br] = v.x;
      Bs[bc * 4 + 1][br] = v.y;
      Bs[bc * 4 + 2][br] = v.z;
      Bs[bc * 4 + 3][br] = v.w;
    }
    __syncthreads();
#pragma unroll
    for (int kkk = 0; kkk < TK; ++kkk) {
      float a[8], b[4];
      *(float4*)&a[0] = *(const float4*)&As[kkk][r0];
      *(float4*)&a[4] = *(const float4*)&As[kkk][r0 + 4];
      *(float4*)&b[0] = *(const float4*)&Bs[kkk][c0];
#pragma unroll
      for (int i = 0; i < 8; ++i)
#pragma unroll
        for (int j = 0; j < 4; ++j) acc[i][j] = fmaf(a[i], b[j], acc[i][j]);
    }
    __syncthreads();
  }
#pragma unroll
  for (int i = 0; i < 8; ++i) {
    float4 v = {acc[i][0], acc[i][1], acc[i][2], acc[i][3]};
    *(float4*)(C + (size_t)(m0 + r0 + i) * DD + e0 + c0) = v;
  }
}

// ---------------------------------------------------------------------------
// K3: sequential gated-delta scan, column-parallel.
// One wave owns one v-column of S for one batch. S[k,col]: lane owns
// k in [8*lane, 8*lane+8) -> 8 VGPRs. 512 WGs (B=4 x 128), 4 waves each.
// Per step: kS = lam * sum_k k[k]*S[k]; verr = beta*(v_t - kS);
//           S = lam*S + k*verr; o = kS + ||k||^2 * verr (since q == k).
// Writes y = static_out + o into d_out (pre-LayerNorm).
// ---------------------------------------------------------------------------
__global__ __launch_bounds__(256) void k_scan(const float* __restrict__ xa,
                                              const float* __restrict__ so,
                                              const float* __restrict__ kkv,
                                              const float* __restrict__ eta_p,
                                              const float* __restrict__ ll_p,
                                              float* __restrict__ y) {
  int b = blockIdx.x >> 7;      // [0,4)
  int cb = blockIdx.x & 127;    // [0,128)
  int wid = threadIdx.x >> 6;   // [0,4)
  int lane = threadIdx.x & 63;
  int col = cb * 4 + wid;       // [0,512)
  float beta = *eta_p;
  float lam = 1.f / (1.f + expf(-*ll_p));
  float S[8] = {0.f, 0.f, 0.f, 0.f, 0.f, 0.f, 0.f, 0.f};
  const float* xab = xa + (size_t)b * LL * DD + lane * 8;
  const float* sob = so + (size_t)b * LL * DD + col;
  const float* kkb = kkv + (size_t)b * LL;
  float* yb = y + (size_t)b * LL * DD + col;
  for (int t = 0; t < LL; ++t) {
    const float* kp = xab + (size_t)t * DD;
    float4 k0 = *(const float4*)kp;
    float4 k1 = *(const float4*)(kp + 4);
    float kv[8] = {k0.x, k0.y, k0.z, k0.w, k1.x, k1.y, k1.z, k1.w};
    // two partial chains for a little ILP
    float d0 = 0.f, d1 = 0.f;
#pragma unroll
    for (int j = 0; j < 4; ++j) {
      d0 = fmaf(kv[j], S[j], d0);
      d1 = fmaf(kv[j + 4], S[j + 4], d1);
    }
    float dot = d0 + d1;
#pragma unroll
    for (int m = 1; m < 64; m <<= 1) dot += __shfl_xor(dot, m, 64);
    float vt = sob[(size_t)t * DD];
    float kk = kkb[t];
    float kS = lam * dot;
    float verr = beta * (vt - kS);
#pragma unroll
    for (int j = 0; j < 8; ++j) S[j] = fmaf(lam, S[j], kv[j] * verr);
    if (lane == 0) yb[(size_t)t * DD] = vt + kS + kk * verr;
  }
}

// ---------------------------------------------------------------------------
// K4: LayerNorm over last dim, in-place on d_out. One wave per row.
// ---------------------------------------------------------------------------
__global__ __launch_bounds__(256) void k_ln(float* __restrict__ y,
                                            const float* __restrict__ gamma,
                                            const float* __restrict__ lbeta) {
  int row = blockIdx.x * 4 + (threadIdx.x >> 6);
  int lane = threadIdx.x & 63;
  float* yr = y + (size_t)row * DD + lane * 8;
  float4 a = *(const float4*)yr;
  float4 b = *(const float4*)(yr + 4);
  float v[8] = {a.x, a.y, a.z, a.w, b.x, b.y, b.z, b.w};
  float s = 0.f, ss = 0.f;
#pragma unroll
  for (int j = 0; j < 8; ++j) {
    s += v[j];
    ss = fmaf(v[j], v[j], ss);
  }
#pragma unroll
  for (int m = 1; m < 64; m <<= 1) {
    s += __shfl_xor(s, m, 64);
    ss += __shfl_xor(ss, m, 64);
  }
  float mu = s * (1.f / DD);
  float var = ss * (1.f / DD) - mu * mu;
  float inv = rsqrtf(var + EPSF);
  const float* gp = gamma + lane * 8;
  const float* bp = lbeta + lane * 8;
  float4 g0 = *(const float4*)gp;
  float4 g1 = *(const float4*)(gp + 4);
  float4 b0 = *(const float4*)bp;
  float4 b1 = *(const float4*)(bp + 4);
  float g[8] = {g0.x, g0.y, g0.z, g0.w, g1.x, g1.y, g1.z, g1.w};
  float bb[8] = {b0.x, b0.y, b0.z, b0.w, b1.x, b1.y, b1.z, b1.w};
#pragma unroll
  for (int j = 0; j < 8; ++j) v[j] = (v[j] - mu) * inv * g[j] + bb[j];
  float4 o0 = {v[0], v[1], v[2], v[3]};
  float4 o1 = {v[4], v[5], v[6], v[7]};
  *(float4*)yr = o0;
  *(float4*)(yr + 4) = o1;
}

// ---------------------------------------------------------------------------
extern "C" void kernel_launch(void* const* d_in, const int* in_sizes, int n_in,
                              void* d_out, int out_size, void* d_ws, size_t ws_size,
                              hipStream_t stream) {
  const float* x     = (const float*)d_in[0];  // [4,2048,512]
  const float* W     = (const float*)d_in[1];  // [512,512]
  const float* eta   = (const float*)d_in[2];  // scalar
  const float* ll    = (const float*)d_in[3];  // scalar (lam_logit)
  const float* gamma = (const float*)d_in[4];  // [512]
  const float* lbeta = (const float*)d_in[5];  // [512]
  float* out = (float*)d_out;                  // [4,2048,512] fp32

  // workspace: xa (16 MB) | so (16 MB) | kk (32 KB)  => needs ~33.6 MB
  float* xa = (float*)d_ws;
  float* so = xa + (size_t)BB * LL * DD;
  float* kk = so + (size_t)BB * LL * DD;

  k_tanh<<<2048, 256, 0, stream>>>(x, xa, kk);
  dim3 ggrid(DD * (BB * LL) / (TM * 512) * 8 / 8, DD / TN);  // (64, 8)
  k_gemm<<<dim3(BB * LL / TM, DD / TN), 256, 0, stream>>>(xa, W, so);
  k_scan<<<512, 256, 0, stream>>>(xa, so, kk, eta, ll, out);
  k_ln<<<2048, 256, 0, stream>>>(out, gamma, lbeta);
}

// Round 3
// 1043.304 us; speedup vs baseline: 1.1118x; 1.1118x over previous
//
#include <hip/hip_runtime.h>
#include <math.h>

#define BB 4
#define LL 2048
#define DD 512
#define CC 64      // chunk length
#define NC 32      // number of chunks
#define EPSF 1e-5f

// ---------------------------------------------------------------------------
// K1: x_act = tanh(x)
// ---------------------------------------------------------------------------
__global__ __launch_bounds__(256) void k_tanh(const float* __restrict__ x,
                                              float* __restrict__ xa) {
  int row  = blockIdx.x * 4 + (threadIdx.x >> 6);
  int lane = threadIdx.x & 63;
  const float* xr = x + (size_t)row * DD + lane * 8;
  float4 a = *(const float4*)xr;
  float4 b = *(const float4*)(xr + 4);
  float v[8] = {a.x, a.y, a.z, a.w, b.x, b.y, b.z, b.w};
#pragma unroll
  for (int j = 0; j < 8; ++j) v[j] = tanhf(v[j]);
  float4 o0 = {v[0], v[1], v[2], v[3]};
  float4 o1 = {v[4], v[5], v[6], v[7]};
  float* xar = xa + (size_t)row * DD + lane * 8;
  *(float4*)xar = o0;
  *(float4*)(xar + 4) = o1;
}

// ---------------------------------------------------------------------------
// K2: static_out = x_act @ W^T  -> written into d_out (holds V for the scan)
// ---------------------------------------------------------------------------
#define TM 128
#define TN 64
#define TK 32
__global__ __launch_bounds__(256) void k_gemm(const float* __restrict__ A,
                                              const float* __restrict__ W,
                                              float* __restrict__ C) {
  __shared__ float As[TK][TM];
  __shared__ float Bs[TK][TN];
  int tid = threadIdx.x;
  int m0 = blockIdx.x * TM;
  int e0 = blockIdx.y * TN;
  int r0 = (tid >> 4) * 8;
  int c0 = (tid & 15) * 4;
  float acc[8][4] = {};
  for (int k0 = 0; k0 < DD; k0 += TK) {
#pragma unroll
    for (int i = 0; i < 4; ++i) {
      int idx = tid + i * 256;
      int amr = idx >> 3, amc = idx & 7;
      float4 v = *(const float4*)(A + (size_t)(m0 + amr) * DD + k0 + amc * 4);
      As[amc * 4 + 0][amr] = v.x;
      As[amc * 4 + 1][amr] = v.y;
      As[amc * 4 + 2][amr] = v.z;
      As[amc * 4 + 3][amr] = v.w;
    }
#pragma unroll
    for (int i = 0; i < 2; ++i) {
      int idx = tid + i * 256;
      int br = idx >> 3, bc = idx & 7;
      float4 v = *(const float4*)(W + (size_t)(e0 + br) * DD + k0 + bc * 4);
      Bs[bc * 4 + 0][br] = v.x;
      Bs[bc * 4 + 1][br] = v.y;
      Bs[bc * 4 + 2][br] = v.z;
      Bs[bc * 4 + 3][br] = v.w;
    }
    __syncthreads();
#pragma unroll
    for (int kkk = 0; kkk < TK; ++kkk) {
      float a[8], b[4];
      *(float4*)&a[0] = *(const float4*)&As[kkk][r0];
      *(float4*)&a[4] = *(const float4*)&As[kkk][r0 + 4];
      *(float4*)&b[0] = *(const float4*)&Bs[kkk][c0];
#pragma unroll
      for (int i = 0; i < 8; ++i)
#pragma unroll
        for (int j = 0; j < 4; ++j) acc[i][j] = fmaf(a[i], b[j], acc[i][j]);
    }
    __syncthreads();
  }
#pragma unroll
  for (int i = 0; i < 8; ++i) {
    float4 v = {acc[i][0], acc[i][1], acc[i][2], acc[i][3]};
    *(float4*)(C + (size_t)(m0 + r0 + i) * DD + e0 + c0) = v;
  }
}

// ---------------------------------------------------------------------------
// K3: per-(b,chunk) prep: G = K K^T, T = (I+A)^{-1}, A[t,s]=beta*lam^{t-s}G[t,s]
// Outputs: Tb = beta*T ; Tc[s,r] = beta*T[s,r]*lam^{r+1} ;
//          Mt[s,r] = lam^{s-r}*G[s,r] (r<s), G[s,s] (r==s), 0 else.
// ---------------------------------------------------------------------------
__global__ __launch_bounds__(256) void k_prep(const float* __restrict__ xa,
                                              const float* __restrict__ eta_p,
                                              const float* __restrict__ ll_p,
                                              float* __restrict__ Tb,
                                              float* __restrict__ Tc,
                                              float* __restrict__ Mt) {
  __shared__ float Gl[64 * 64];
  __shared__ float Klp[64 * 64];
  __shared__ float Tl[64 * 64];
  int bc = blockIdx.x;
  int b = bc >> 5, c = bc & 31;
  int tid = threadIdx.x;
  float beta = *eta_p;
  float lam = 1.f / (1.f + expf(-*ll_p));
  const float* Kg = xa + (size_t)(b * LL + c * CC) * DD;
  int tq = tid >> 4, sq = tid & 15;
  float acc[4][4] = {};
  for (int sl = 0; sl < 8; ++sl) {
    __syncthreads();
#pragma unroll
    for (int i = 0; i < 4; ++i) {
      int f4i = tid + i * 256;
      int r = f4i >> 4;
      int kq = (f4i & 15) * 4;
      float4 v = *(const float4*)(Kg + (size_t)r * DD + sl * 64 + kq);
      *(float4*)&Klp[r * 64 + (kq ^ ((r & 7) << 2))] = v;
    }
    __syncthreads();
#pragma unroll
    for (int k4 = 0; k4 < 16; ++k4) {
      int k = k4 * 4;
      float4 ta[4], sa[4];
#pragma unroll
      for (int i = 0; i < 4; ++i) {
        int tr = tq + 16 * i;
        ta[i] = *(const float4*)&Klp[tr * 64 + (k ^ ((tr & 7) << 2))];
      }
#pragma unroll
      for (int j = 0; j < 4; ++j) {
        int sr = sq + 16 * j;
        sa[j] = *(const float4*)&Klp[sr * 64 + (k ^ ((sr & 7) << 2))];
      }
#pragma unroll
      for (int i = 0; i < 4; ++i)
#pragma unroll
        for (int j = 0; j < 4; ++j)
          acc[i][j] += ta[i].x * sa[j].x + ta[i].y * sa[j].y +
                       ta[i].z * sa[j].z + ta[i].w * sa[j].w;
    }
  }
  __syncthreads();
#pragma unroll
  for (int i = 0; i < 4; ++i)
#pragma unroll
    for (int j = 0; j < 4; ++j) Gl[(tq + 16 * i) * 64 + (sq + 16 * j)] = acc[i][j];
  __syncthreads();
  // forward substitution for T = (I+A)^{-1}; lane = column j
  if (tid < 64) {
    int j = tid;
    for (int t = 0; t < 64; ++t) {
      float a = 0.f;
      float pf = lam;
      for (int s = t - 1; s >= 0; --s) {
        a = fmaf(pf * beta * Gl[t * 64 + s], Tl[s * 64 + j], a);
        pf *= lam;
      }
      Tl[t * 64 + j] = ((t == j) ? 1.f : 0.f) - a;
    }
  }
  __syncthreads();
  float* pw = Klp;  // reuse
  if (tid <= 64) pw[tid] = powf(lam, (float)tid);
  __syncthreads();
  float* tb = Tb + (size_t)bc * 64 * 64;
  float* tc = Tc + (size_t)bc * 64 * 64;
  float* mt = Mt + (size_t)bc * 64 * 64;
#pragma unroll
  for (int i = 0; i < 16; ++i) {
    int idx = tid + i * 256;
    int s = idx >> 6, r = idx & 63;
    float tv = Tl[s * 64 + r];
    tb[idx] = beta * tv;
    tc[idx] = beta * tv * pw[r + 1];
    mt[idx] = (r < s) ? pw[s - r] * Gl[s * 64 + r]
                      : ((r == s) ? Gl[s * 64 + r] : 0.f);
  }
}

// ---------------------------------------------------------------------------
// K4: chunked scan. One WG = (batch b, v-block of 8 columns). 256 threads.
//   A: U[t][v] = sum_k K[t][k] St[v][k]
//   B: W[s][v] = sum_r Tb[s][r]V[r][v] - Tc[s][r]U[r][v]
//   C: O[s][v] = lam^{s+1}U[s][v] + sum_r Mt[s][r]W[r][v]; y = V + O
//   D: St[v][k] = lam^64 * St[v][k] + sum_s lam^{63-s} W[s][v] K[s][k]
// ---------------------------------------------------------------------------
__global__ __launch_bounds__(256) void k_scan2(const float* __restrict__ xa,
                                               const float* __restrict__ Tb,
                                               const float* __restrict__ Tc,
                                               const float* __restrict__ Mt,
                                               const float* __restrict__ ll_p,
                                               float* __restrict__ y) {
  __shared__ float Kl[64 * 128];
  __shared__ float St[8 * 512];
  __shared__ float Ut[8 * 68];
  __shared__ float Wt[8 * 68];
  __shared__ float Vt[8 * 68];
  __shared__ float pwl[66];
  int b = blockIdx.x >> 6;
  int vb = blockIdx.x & 63;
  int v0 = vb * 8;
  int tid = threadIdx.x;
  float lam = 1.f / (1.f + expf(-*ll_p));
  if (tid <= 64) pwl[tid] = powf(lam, (float)tid);
#pragma unroll
  for (int i = 0; i < 16; ++i) St[tid + i * 256] = 0.f;
  int tp = tid >> 3;
  int av = tid & 7;
  int cs = tid >> 2;
  int cvp = (tid & 3) * 2;
  int dkq = tid >> 3;
  int dv = tid & 7;
  const float* xab = xa + (size_t)b * LL * DD;
  float* yb = y + (size_t)b * LL * DD;
  float l64 = 1.f / (1.f + expf(-*ll_p));
  { float t = l64; for (int i = 0; i < 6; ++i) t *= t; l64 = t; }  // lam^64

  for (int c = 0; c < NC; ++c) {
    const float* Kg = xab + (size_t)c * CC * DD;
    // ---------- phase A ----------
    float ua0 = 0.f, ua1 = 0.f;
    int t0 = tp * 2;
    for (int sl = 0; sl < 4; ++sl) {
      __syncthreads();
#pragma unroll
      for (int i = 0; i < 8; ++i) {
        int f4i = tid + i * 256;
        int r = f4i >> 5;
        int kq = (f4i & 31) * 4;
        float4 vv = *(const float4*)(Kg + (size_t)r * DD + sl * 128 + kq);
        *(float4*)&Kl[r * 128 + (kq ^ ((r & 7) << 2))] = vv;
      }
      __syncthreads();
#pragma unroll
      for (int k4 = 0; k4 < 32; ++k4) {
        int k = k4 * 4;
        float4 a0 = *(const float4*)&Kl[t0 * 128 + (k ^ ((t0 & 7) << 2))];
        float4 a1 = *(const float4*)&Kl[(t0 + 1) * 128 + (k ^ (((t0 + 1) & 7) << 2))];
        int kst = sl * 128 + k;
        float4 sv = *(const float4*)&St[av * 512 + (kst ^ (av << 2))];
        ua0 += a0.x * sv.x + a0.y * sv.y + a0.z * sv.z + a0.w * sv.w;
        ua1 += a1.x * sv.x + a1.y * sv.y + a1.z * sv.z + a1.w * sv.w;
      }
    }
    Ut[av * 68 + t0] = ua0;
    Ut[av * 68 + t0 + 1] = ua1;
    // ---------- load V ----------
    if (tid < 128) {
      int s = tid >> 1, vq = (tid & 1) * 4;
      float4 vv = *(const float4*)(yb + (size_t)(c * CC + s) * DD + v0 + vq);
      Vt[(vq + 0) * 68 + s] = vv.x;
      Vt[(vq + 1) * 68 + s] = vv.y;
      Vt[(vq + 2) * 68 + s] = vv.z;
      Vt[(vq + 3) * 68 + s] = vv.w;
    }
    __syncthreads();
    // ---------- phase B ----------
    {
      const float* tbr = Tb + ((size_t)(b * NC + c) * 64 + cs) * 64;
      const float* tcr = Tc + ((size_t)(b * NC + c) * 64 + cs) * 64;
      float w0 = 0.f, w1 = 0.f;
#pragma unroll
      for (int r4 = 0; r4 < 16; ++r4) {
        int r = r4 * 4;
        float4 tb4 = *(const float4*)(tbr + r);
        float4 tc4 = *(const float4*)(tcr + r);
        float4 va = *(const float4*)&Vt[cvp * 68 + r];
        float4 vbb = *(const float4*)&Vt[(cvp + 1) * 68 + r];
        float4 u0 = *(const float4*)&Ut[cvp * 68 + r];
        float4 u1 = *(const float4*)&Ut[(cvp + 1) * 68 + r];
        w0 += tb4.x * va.x + tb4.y * va.y + tb4.z * va.z + tb4.w * va.w;
        w0 -= tc4.x * u0.x + tc4.y * u0.y + tc4.z * u0.z + tc4.w * u0.w;
        w1 += tb4.x * vbb.x + tb4.y * vbb.y + tb4.z * vbb.z + tb4.w * vbb.w;
        w1 -= tc4.x * u1.x + tc4.y * u1.y + tc4.z * u1.z + tc4.w * u1.w;
      }
      Wt[cvp * 68 + cs] = w0;
      Wt[(cvp + 1) * 68 + cs] = w1;
    }
    __syncthreads();
    // ---------- phase C ----------
    {
      const float* mtr = Mt + ((size_t)(b * NC + c) * 64 + cs) * 64;
      float o0 = pwl[cs + 1] * Ut[cvp * 68 + cs];
      float o1 = pwl[cs + 1] * Ut[(cvp + 1) * 68 + cs];
#pragma unroll
      for (int r4 = 0; r4 < 16; ++r4) {
        int r = r4 * 4;
        float4 m4 = *(const float4*)(mtr + r);
        float4 w0 = *(const float4*)&Wt[cvp * 68 + r];
        float4 w1 = *(const float4*)&Wt[(cvp + 1) * 68 + r];
        o0 += m4.x * w0.x + m4.y * w0.y + m4.z * w0.z + m4.w * w0.w;
        o1 += m4.x * w1.x + m4.y * w1.y + m4.z * w1.z + m4.w * w1.w;
      }
      float2 yo;
      yo.x = Vt[cvp * 68 + cs] + o0;
      yo.y = Vt[(cvp + 1) * 68 + cs] + o1;
      *(float2*)(yb + (size_t)(c * CC + cs) * DD + v0 + cvp) = yo;
    }
    // ---------- phase D ----------
    for (int sl = 0; sl < 4; ++sl) {
      __syncthreads();
#pragma unroll
      for (int i = 0; i < 8; ++i) {
        int f4i = tid + i * 256;
        int r = f4i >> 5;
        int kq = (f4i & 31) * 4;
        float4 vv = *(const float4*)(Kg + (size_t)r * DD + sl * 128 + kq);
        *(float4*)&Kl[r * 128 + (kq ^ ((r & 7) << 2))] = vv;
      }
      __syncthreads();
      int kst = sl * 128 + dkq * 4;
      float4 sacc = *(const float4*)&St[dv * 512 + (kst ^ (dv << 2))];
      sacc.x *= l64; sacc.y *= l64; sacc.z *= l64; sacc.w *= l64;  // inter-chunk decay
#pragma unroll 4
      for (int s = 0; s < 64; ++s) {
        float wd = Wt[dv * 68 + s] * pwl[63 - s];
        float4 kf = *(const float4*)&Kl[s * 128 + ((dkq * 4) ^ ((s & 7) << 2))];
        sacc.x = fmaf(wd, kf.x, sacc.x);
        sacc.y = fmaf(wd, kf.y, sacc.y);
        sacc.z = fmaf(wd, kf.z, sacc.z);
        sacc.w = fmaf(wd, kf.w, sacc.w);
      }
      *(float4*)&St[dv * 512 + (kst ^ (dv << 2))] = sacc;
    }
  }
}

// ---------------------------------------------------------------------------
// K5: LayerNorm in-place on d_out.
// ---------------------------------------------------------------------------
__global__ __launch_bounds__(256) void k_ln(float* __restrict__ y,
                                            const float* __restrict__ gamma,
                                            const float* __restrict__ lbeta) {
  int row = blockIdx.x * 4 + (threadIdx.x >> 6);
  int lane = threadIdx.x & 63;
  float* yr = y + (size_t)row * DD + lane * 8;
  float4 a = *(const float4*)yr;
  float4 b = *(const float4*)(yr + 4);
  float v[8] = {a.x, a.y, a.z, a.w, b.x, b.y, b.z, b.w};
  float s = 0.f, ss = 0.f;
#pragma unroll
  for (int j = 0; j < 8; ++j) {
    s += v[j];
    ss = fmaf(v[j], v[j], ss);
  }
#pragma unroll
  for (int m = 1; m < 64; m <<= 1) {
    s += __shfl_xor(s, m, 64);
    ss += __shfl_xor(ss, m, 64);
  }
  float mu = s * (1.f / DD);
  float var = ss * (1.f / DD) - mu * mu;
  float inv = rsqrtf(var + EPSF);
  const float* gp = gamma + lane * 8;
  const float* bp = lbeta + lane * 8;
  float4 g0 = *(const float4*)gp;
  float4 g1 = *(const float4*)(gp + 4);
  float4 b0 = *(const float4*)bp;
  float4 b1 = *(const float4*)(bp + 4);
  float g[8] = {g0.x, g0.y, g0.z, g0.w, g1.x, g1.y, g1.z, g1.w};
  float bb[8] = {b0.x, b0.y, b0.z, b0.w, b1.x, b1.y, b1.z, b1.w};
#pragma unroll
  for (int j = 0; j < 8; ++j) v[j] = (v[j] - mu) * inv * g[j] + bb[j];
  float4 o0 = {v[0], v[1], v[2], v[3]};
  float4 o1 = {v[4], v[5], v[6], v[7]};
  *(float4*)yr = o0;
  *(float4*)(yr + 4) = o1;
}

// ---------------------------------------------------------------------------
extern "C" void kernel_launch(void* const* d_in, const int* in_sizes, int n_in,
                              void* d_out, int out_size, void* d_ws, size_t ws_size,
                              hipStream_t stream) {
  const float* x     = (const float*)d_in[0];
  const float* W     = (const float*)d_in[1];
  const float* eta   = (const float*)d_in[2];
  const float* ll    = (const float*)d_in[3];
  const float* gamma = (const float*)d_in[4];
  const float* lbeta = (const float*)d_in[5];
  float* out = (float*)d_out;

  float* xa = (float*)d_ws;
  float* Tb = xa + (size_t)BB * LL * DD;
  float* Tc = Tb + (size_t)BB * NC * 64 * 64;
  float* Mt = Tc + (size_t)BB * NC * 64 * 64;

  k_tanh<<<2048, 256, 0, stream>>>(x, xa);
  k_gemm<<<dim3(BB * LL / TM, DD / TN), 256, 0, stream>>>(xa, W, out);
  k_prep<<<BB * NC, 256, 0, stream>>>(xa, eta, ll, Tb, Tc, Mt);
  k_scan2<<<256, 256, 0, stream>>>(xa, Tb, Tc, Mt, ll, out);
  k_ln<<<2048, 256, 0, stream>>>(out, gamma, lbeta);
}

// Round 4
// 211.019 us; speedup vs baseline: 5.4970x; 4.9441x over previous
//
#include <hip/hip_runtime.h>
#include <math.h>

#define BB 4
#define LL 2048
#define DD 512
#define CC 64      // chunk length
#define NC 32      // number of chunks
#define VB 8       // v-columns per workgroup
#define EPSF 1e-5f

typedef unsigned int u32;
typedef unsigned short u16;
typedef __attribute__((ext_vector_type(4))) u32 u32x4;
typedef __attribute__((ext_vector_type(4))) float f32x4;
typedef __attribute__((ext_vector_type(8))) __bf16 bf16x8;
typedef __attribute__((ext_vector_type(8))) u16 u16x8;

__device__ __forceinline__ u16 f2bf(float f) {  // RNE float->bf16
  u32 u = __builtin_bit_cast(u32, f);
  u = (u + 0x7fffu + ((u >> 16) & 1u)) >> 16;
  return (u16)u;
}
__device__ __forceinline__ int sx6(int s) { return (s ^ (s >> 3)) & 7; }  // 16B-slot xor
__device__ __forceinline__ bf16x8 ldf(const u16* p) {
  return __builtin_bit_cast(bf16x8, *(const u32x4*)p);
}
__device__ __forceinline__ bf16x8 bcv(u32x4 v) { return __builtin_bit_cast(bf16x8, v); }

// ---------------------------------------------------------------------------
// K1: x_act = tanh(x): fp32 copy (for k_prep) + pre-swizzled bf16 copy (scan)
// kbs layout: flat row*512 + (k ^ (sx6(row&63)<<3)), bf16
// ---------------------------------------------------------------------------
__global__ __launch_bounds__(256) void k_tanh(const float* __restrict__ x,
                                              float* __restrict__ xa,
                                              u16* __restrict__ kbs) {
  int row  = blockIdx.x * 4 + (threadIdx.x >> 6);
  int lane = threadIdx.x & 63;
  const float* xr = x + (size_t)row * DD + lane * 8;
  float4 a = *(const float4*)xr;
  float4 b = *(const float4*)(xr + 4);
  float v[8] = {a.x, a.y, a.z, a.w, b.x, b.y, b.z, b.w};
#pragma unroll
  for (int j = 0; j < 8; ++j) v[j] = tanhf(v[j]);
  float* xar = xa + (size_t)row * DD + lane * 8;
  *(float4*)xar = make_float4(v[0], v[1], v[2], v[3]);
  *(float4*)(xar + 4) = make_float4(v[4], v[5], v[6], v[7]);
  u16 h[8];
#pragma unroll
  for (int j = 0; j < 8; ++j) h[j] = f2bf(v[j]);
  u32x4 pk;
  pk[0] = (u32)h[0] | ((u32)h[1] << 16);
  pk[1] = (u32)h[2] | ((u32)h[3] << 16);
  pk[2] = (u32)h[4] | ((u32)h[5] << 16);
  pk[3] = (u32)h[6] | ((u32)h[7] << 16);
  int s = row & 63;
  int k0 = (lane * 8) ^ (sx6(s) << 3);
  *(u32x4*)(kbs + (size_t)row * DD + k0) = pk;
}

// ---------------------------------------------------------------------------
// K1b: W -> bf16 copy (row-major, unswizzled; consumed as global A-fragments)
// ---------------------------------------------------------------------------
__global__ __launch_bounds__(256) void k_cvtW(const float* __restrict__ W,
                                              u16* __restrict__ wbb) {
  int idx = (blockIdx.x * 256 + threadIdx.x) * 8;
  float4 a = *(const float4*)(W + idx);
  float4 b = *(const float4*)(W + idx + 4);
  float v[8] = {a.x, a.y, a.z, a.w, b.x, b.y, b.z, b.w};
  u16 h[8];
#pragma unroll
  for (int j = 0; j < 8; ++j) h[j] = f2bf(v[j]);
  u32x4 pk;
  pk[0] = (u32)h[0] | ((u32)h[1] << 16);
  pk[1] = (u32)h[2] | ((u32)h[3] << 16);
  pk[2] = (u32)h[4] | ((u32)h[5] << 16);
  pk[3] = (u32)h[6] | ((u32)h[7] << 16);
  *(u32x4*)(wbb + idx) = pk;
}

// ---------------------------------------------------------------------------
// K2: per-(b,chunk) prep (fp32 internally, bf16 outputs [s][r] row-major):
//   tbb = beta*T ; tcb = -beta*T[s][r]*lam^{r+1} (NEGATED for mfma-add) ;
//   mtb[s][r] = lam^{s-r}*G[s][r] (r<s), G[s][s] (r==s), 0 else.
// ---------------------------------------------------------------------------
__global__ __launch_bounds__(256) void k_prep(const float* __restrict__ xa,
                                              const float* __restrict__ eta_p,
                                              const float* __restrict__ ll_p,
                                              u16* __restrict__ tbb,
                                              u16* __restrict__ tcb,
                                              u16* __restrict__ mtb) {
  __shared__ float Gl[64 * 64];
  __shared__ float Gs[64 * 64];   // pre-scaled coefficients (reuses stage role)
  __shared__ float Tl[64 * 64];
  __shared__ float Klp[64 * 64];
  __shared__ float pw[72];
  int bc = blockIdx.x;
  int b = bc >> 5, c = bc & 31;
  int tid = threadIdx.x;
  float beta = *eta_p;
  float lam = 1.f / (1.f + expf(-*ll_p));
  if (tid <= 64) pw[tid] = powf(lam, (float)tid);
  const float* Kg = xa + (size_t)(b * LL + c * CC) * DD;
  int tq = tid >> 4, sq = tid & 15;
  float acc[4][4] = {};
  for (int sl = 0; sl < 8; ++sl) {
    __syncthreads();
#pragma unroll
    for (int i = 0; i < 4; ++i) {
      int f4i = tid + i * 256;
      int r = f4i >> 4;
      int kq = (f4i & 15) * 4;
      float4 v = *(const float4*)(Kg + (size_t)r * DD + sl * 64 + kq);
      *(float4*)&Klp[r * 64 + (kq ^ ((r & 7) << 2))] = v;
    }
    __syncthreads();
#pragma unroll
    for (int k4 = 0; k4 < 16; ++k4) {
      int k = k4 * 4;
      float4 ta[4], sa[4];
#pragma unroll
      for (int i = 0; i < 4; ++i) {
        int tr = tq + 16 * i;
        ta[i] = *(const float4*)&Klp[tr * 64 + (k ^ ((tr & 7) << 2))];
      }
#pragma unroll
      for (int j = 0; j < 4; ++j) {
        int sr = sq + 16 * j;
        sa[j] = *(const float4*)&Klp[sr * 64 + (k ^ ((sr & 7) << 2))];
      }
#pragma unroll
      for (int i = 0; i < 4; ++i)
#pragma unroll
        for (int j = 0; j < 4; ++j)
          acc[i][j] += ta[i].x * sa[j].x + ta[i].y * sa[j].y +
                       ta[i].z * sa[j].z + ta[i].w * sa[j].w;
    }
  }
  __syncthreads();
#pragma unroll
  for (int i = 0; i < 4; ++i)
#pragma unroll
    for (int j = 0; j < 4; ++j) Gl[(tq + 16 * i) * 64 + (sq + 16 * j)] = acc[i][j];
  __syncthreads();
  // pre-scaled coefficients for forward substitution
#pragma unroll
  for (int i = 0; i < 16; ++i) {
    int idx = tid + i * 256;
    int t = idx >> 6, s = idx & 63;
    Gs[idx] = (s < t) ? beta * pw[t - s] * Gl[idx] : 0.f;
  }
  __syncthreads();
  // forward substitution for T = (I+A)^{-1}; lane = column j
  if (tid < 64) {
    int j = tid;
    for (int t = 0; t < 64; ++t) {
      float a = 0.f;
      for (int s = 0; s < t; ++s) a = fmaf(Gs[t * 64 + s], Tl[s * 64 + j], a);
      Tl[t * 64 + j] = ((t == j) ? 1.f : 0.f) - a;
    }
  }
  __syncthreads();
  u16* tb = tbb + (size_t)bc * 64 * 64;
  u16* tc = tcb + (size_t)bc * 64 * 64;
  u16* mt = mtb + (size_t)bc * 64 * 64;
#pragma unroll
  for (int i = 0; i < 16; ++i) {
    int idx = tid + i * 256;
    int s = idx >> 6, r = idx & 63;
    float tv = Tl[s * 64 + r];
    tb[idx] = f2bf(beta * tv);
    tc[idx] = f2bf(-(beta * tv * pw[r + 1]));  // negated
    mt[idx] = f2bf((r < s) ? pw[s - r] * Gl[s * 64 + r]
                           : ((r == s) ? Gl[s * 64 + r] : 0.f));
  }
}

// ---------------------------------------------------------------------------
// K3: MFMA chunked scan. WG = (b, v-block of 8). 256 thr (4 waves), 1 WG/CU.
// All phases computed transposed (M = v = 16, rows >=8 are exact zeros).
//   V:  V^T = W . K^T          (fused static_out)
//   A:  U^T = S^T . K^T
//   B:  W^T = V^T.Tb^T + U^T.(-Tc)^T
//   C:  O^T = diag_s(lam^{s+1}) U^T + W^T.Mt^T ; y = V + O
//   D:  S^T = lam^64 S^T + Wsc^T . K   (Wsc = diag(lam^{63-s}) W)
// S lives in fp32 MFMA accumulators; bf16 copy in LDS for A-fragments.
// ---------------------------------------------------------------------------
__global__ __launch_bounds__(256) void k_scan3(const u16* __restrict__ kbs,
                                               const u16* __restrict__ wbb,
                                               const u16* __restrict__ tbb,
                                               const u16* __restrict__ tcb,
                                               const u16* __restrict__ mtb,
                                               const float* __restrict__ ll_p,
                                               float* __restrict__ y) {
  __shared__ __align__(16) u16 Kl[2][CC * DD];  // 2 x 64 KB, pre-swizzled
  __shared__ __align__(16) u16 Sb[16 * DD];     // 16 KB bf16 state copy
  __shared__ __align__(16) u16 Vt[16 * 64];
  __shared__ __align__(16) u16 Ut[16 * 64];
  __shared__ __align__(16) u16 Wt[16 * 64];
  __shared__ __align__(16) u16 Ws[16 * 64];
  __shared__ float pwl[72];

  int b = blockIdx.x >> 6;
  int vb = blockIdx.x & 63;
  int v0 = vb * VB;
  int tid = threadIdx.x;
  int wid = tid >> 6, lane = tid & 63;
  int lo = lane & 15, hi = lane >> 4;

  float lam = 1.f / (1.f + expf(-*ll_p));
  if (tid <= 64) pwl[tid] = powf(lam, (float)tid);
  // zero state copy + padding tiles
  {
    u32x4 z = {0u, 0u, 0u, 0u};
    for (int i = tid; i < 16 * DD / 8; i += 256) *((u32x4*)Sb + i) = z;
    if (tid < 128) {
      *((u32x4*)Vt + tid) = z;
      *((u32x4*)Ut + tid) = z;
      *((u32x4*)Wt + tid) = z;
      *((u32x4*)Ws + tid) = z;
    }
  }
  const u16* kb_b = kbs + (size_t)b * LL * DD;
  // prologue: stage chunk 0
  {
    u32x4 st[16];
#pragma unroll
    for (int r = 0; r < 16; ++r) st[r] = *(const u32x4*)(kb_b + r * 2048 + tid * 8);
#pragma unroll
    for (int r = 0; r < 16; ++r) *(u32x4*)(Kl[0] + r * 2048 + tid * 8) = st[r];
  }
  // preload W A-fragments (rows v0+lo, all K) - chunk invariant
  u32x4 wf[16];
#pragma unroll
  for (int k = 0; k < 16; ++k)
    wf[k] = *(const u32x4*)(wbb + (size_t)((v0 + lo) & 511) * DD + hi * 8 + k * 32);

  f32x4 Sa[8];
#pragma unroll
  for (int t = 0; t < 8; ++t) Sa[t] = (f32x4){0.f, 0.f, 0.f, 0.f};
  __syncthreads();

  int sidx = 16 * wid + lo;                // owned s/t column in V/A/B/C
  int mKrow = sx6(sidx) << 3;              // swizzle for Kl row `sidx`
  int mLo = sx6(lo) << 3;                  // swizzle for v-row `lo` tiles
  float lam64 = pwl[64];
  float csc = pwl[sidx + 1];               // lam^{s+1}
  float dsc = pwl[63 - sidx];              // lam^{63-s}
  float* yb = y + (size_t)b * LL * DD;

  for (int c = 0; c < NC; ++c) {
    const u16* Kc = Kl[c & 1];
    // issue next-chunk stage loads (land ~a full chunk later)
    u32x4 st[16];
    if (c + 1 < NC) {
      const u16* src = kb_b + (size_t)(c + 1) * CC * DD;
#pragma unroll
      for (int r = 0; r < 16; ++r) st[r] = *(const u32x4*)(src + r * 2048 + tid * 8);
    }
    // prefetch T fragments for this chunk (B-frags: [s][r], r contiguous)
    size_t tbase = ((size_t)(b * NC + c) * 64 + sidx) * 64 + hi * 8;
    u32x4 tb0 = *(const u32x4*)(tbb + tbase);
    u32x4 tb1 = *(const u32x4*)(tbb + tbase + 32);
    u32x4 tc0 = *(const u32x4*)(tcb + tbase);
    u32x4 tc1 = *(const u32x4*)(tcb + tbase + 32);
    u32x4 mt0 = *(const u32x4*)(mtb + tbase);
    u32x4 mt1 = *(const u32x4*)(mtb + tbase + 32);

    // ---- phases V + A (share K B-fragments) ----
    f32x4 Va = {0.f, 0.f, 0.f, 0.f};
    f32x4 Ua = {0.f, 0.f, 0.f, 0.f};
#pragma unroll
    for (int k = 0; k < 16; ++k) {
      int col = hi * 8 + k * 32;
      bf16x8 kB = ldf(Kc + sidx * DD + (col ^ mKrow));
      bf16x8 sA = ldf(Sb + lo * DD + (col ^ mLo));
      Va = __builtin_amdgcn_mfma_f32_16x16x32_bf16(bcv(wf[k]), kB, Va, 0, 0, 0);
      Ua = __builtin_amdgcn_mfma_f32_16x16x32_bf16(sA, kB, Ua, 0, 0, 0);
    }
#pragma unroll
    for (int r = 0; r < 4; ++r) {
      int v = 4 * hi + r;
      int idx = v * 64 + (sidx ^ (sx6(v) << 3));
      if (hi < 2) Vt[idx] = f2bf(Va[r]);
      Ut[idx] = f2bf(Ua[r]);
    }
    __syncthreads();
    // ---- phase B ----
    f32x4 Wa = {0.f, 0.f, 0.f, 0.f};
    {
      bf16x8 vf0 = ldf(Vt + lo * 64 + ((hi * 8) ^ mLo));
      bf16x8 vf1 = ldf(Vt + lo * 64 + ((hi * 8 + 32) ^ mLo));
      bf16x8 uf0 = ldf(Ut + lo * 64 + ((hi * 8) ^ mLo));
      bf16x8 uf1 = ldf(Ut + lo * 64 + ((hi * 8 + 32) ^ mLo));
      Wa = __builtin_amdgcn_mfma_f32_16x16x32_bf16(vf0, bcv(tb0), Wa, 0, 0, 0);
      Wa = __builtin_amdgcn_mfma_f32_16x16x32_bf16(vf1, bcv(tb1), Wa, 0, 0, 0);
      Wa = __builtin_amdgcn_mfma_f32_16x16x32_bf16(uf0, bcv(tc0), Wa, 0, 0, 0);
      Wa = __builtin_amdgcn_mfma_f32_16x16x32_bf16(uf1, bcv(tc1), Wa, 0, 0, 0);
    }
#pragma unroll
    for (int r = 0; r < 4; ++r) {
      int v = 4 * hi + r;
      int idx = v * 64 + (sidx ^ (sx6(v) << 3));
      Wt[idx] = f2bf(Wa[r]);
      Ws[idx] = f2bf(Wa[r] * dsc);
    }
    __syncthreads();
    // ---- phase C + y store ----
    f32x4 Oa = Ua * csc;
    {
      bf16x8 wf0 = ldf(Wt + lo * 64 + ((hi * 8) ^ mLo));
      bf16x8 wf1 = ldf(Wt + lo * 64 + ((hi * 8 + 32) ^ mLo));
      Oa = __builtin_amdgcn_mfma_f32_16x16x32_bf16(wf0, bcv(mt0), Oa, 0, 0, 0);
      Oa = __builtin_amdgcn_mfma_f32_16x16x32_bf16(wf1, bcv(mt1), Oa, 0, 0, 0);
    }
    if (hi < 2) {
      float4 yo = make_float4(Va[0] + Oa[0], Va[1] + Oa[1],
                              Va[2] + Oa[2], Va[3] + Oa[3]);
      *(float4*)(yb + (size_t)(c * CC + sidx) * DD + v0 + 4 * hi) = yo;
    }
    // ---- phase D: S = lam^64*S + Ws^T . K ----
    bf16x8 ws0 = ldf(Ws + lo * 64 + ((hi * 8) ^ mLo));
    bf16x8 ws1 = ldf(Ws + lo * 64 + ((hi * 8 + 32) ^ mLo));
#pragma unroll
    for (int t = 0; t < 8; ++t) {
      int kc = 16 * (8 * wid + t) + lo;
      u16x8 e0, e1;
#pragma unroll
      for (int j = 0; j < 8; ++j) {
        int s0 = 8 * hi + j;
        e0[j] = Kc[s0 * DD + (kc ^ (sx6(s0) << 3))];
        int s1 = s0 + 32;
        e1[j] = Kc[s1 * DD + (kc ^ (sx6(s1) << 3))];
      }
      f32x4 acc = Sa[t] * lam64;
      acc = __builtin_amdgcn_mfma_f32_16x16x32_bf16(ws0, __builtin_bit_cast(bf16x8, e0), acc, 0, 0, 0);
      acc = __builtin_amdgcn_mfma_f32_16x16x32_bf16(ws1, __builtin_bit_cast(bf16x8, e1), acc, 0, 0, 0);
      Sa[t] = acc;
    }
    // write bf16 state copy (rows v<8; rows 8-15 remain zero)
    if (hi < 2) {
#pragma unroll
      for (int t = 0; t < 8; ++t) {
        int kc = 16 * (8 * wid + t) + lo;
#pragma unroll
        for (int r = 0; r < 4; ++r) {
          int v = 4 * hi + r;
          Sb[v * DD + (kc ^ (sx6(v) << 3))] = f2bf(Sa[t][r]);
        }
      }
    }
    // commit staged K for next chunk
    if (c + 1 < NC) {
#pragma unroll
      for (int r = 0; r < 16; ++r)
        *(u32x4*)(Kl[(c & 1) ^ 1] + r * 2048 + tid * 8) = st[r];
    }
    __syncthreads();
  }
}

// ---------------------------------------------------------------------------
// K4: LayerNorm in-place on d_out.
// ---------------------------------------------------------------------------
__global__ __launch_bounds__(256) void k_ln(float* __restrict__ y,
                                            const float* __restrict__ gamma,
                                            const float* __restrict__ lbeta) {
  int row = blockIdx.x * 4 + (threadIdx.x >> 6);
  int lane = threadIdx.x & 63;
  float* yr = y + (size_t)row * DD + lane * 8;
  float4 a = *(const float4*)yr;
  float4 b = *(const float4*)(yr + 4);
  float v[8] = {a.x, a.y, a.z, a.w, b.x, b.y, b.z, b.w};
  float s = 0.f, ss = 0.f;
#pragma unroll
  for (int j = 0; j < 8; ++j) {
    s += v[j];
    ss = fmaf(v[j], v[j], ss);
  }
#pragma unroll
  for (int m = 1; m < 64; m <<= 1) {
    s += __shfl_xor(s, m, 64);
    ss += __shfl_xor(ss, m, 64);
  }
  float mu = s * (1.f / DD);
  float var = ss * (1.f / DD) - mu * mu;
  float inv = rsqrtf(var + EPSF);
  const float* gp = gamma + lane * 8;
  const float* bp = lbeta + lane * 8;
  float4 g0 = *(const float4*)gp;
  float4 g1 = *(const float4*)(gp + 4);
  float4 b0 = *(const float4*)bp;
  float4 b1 = *(const float4*)(bp + 4);
  float g[8] = {g0.x, g0.y, g0.z, g0.w, g1.x, g1.y, g1.z, g1.w};
  float bb[8] = {b0.x, b0.y, b0.z, b0.w, b1.x, b1.y, b1.z, b1.w};
#pragma unroll
  for (int j = 0; j < 8; ++j) v[j] = (v[j] - mu) * inv * g[j] + bb[j];
  *(float4*)yr = make_float4(v[0], v[1], v[2], v[3]);
  *(float4*)(yr + 4) = make_float4(v[4], v[5], v[6], v[7]);
}

// ---------------------------------------------------------------------------
extern "C" void kernel_launch(void* const* d_in, const int* in_sizes, int n_in,
                              void* d_out, int out_size, void* d_ws, size_t ws_size,
                              hipStream_t stream) {
  const float* x     = (const float*)d_in[0];
  const float* W     = (const float*)d_in[1];
  const float* eta   = (const float*)d_in[2];
  const float* ll    = (const float*)d_in[3];
  const float* gamma = (const float*)d_in[4];
  const float* lbeta = (const float*)d_in[5];
  float* out = (float*)d_out;

  // workspace: xa fp32 (16MB) | kbs bf16 (8MB) | wbb bf16 (0.5MB) | tbb/tcb/mtb bf16 (3MB)
  float* xa = (float*)d_ws;
  u16* kbs = (u16*)(xa + (size_t)BB * LL * DD);
  u16* wbb = kbs + (size_t)BB * LL * DD;
  u16* tbb = wbb + (size_t)DD * DD;
  u16* tcb = tbb + (size_t)BB * NC * 64 * 64;
  u16* mtb = tcb + (size_t)BB * NC * 64 * 64;

  k_tanh<<<2048, 256, 0, stream>>>(x, xa, kbs);
  k_cvtW<<<128, 256, 0, stream>>>(W, wbb);
  k_prep<<<BB * NC, 256, 0, stream>>>(xa, eta, ll, tbb, tcb, mtb);
  k_scan3<<<256, 256, 0, stream>>>(kbs, wbb, tbb, tcb, mtb, ll, out);
  k_ln<<<2048, 256, 0, stream>>>(out, gamma, lbeta);
}

// Round 5
// 208.198 us; speedup vs baseline: 5.5715x; 1.0136x over previous
//
#include <hip/hip_runtime.h>
#include <math.h>

#define BB 4
#define LL 2048
#define DD 512
#define CC 64      // chunk length
#define NC 32      // number of chunks
#define VB 8       // v-columns owned per workgroup
#define EPSF 1e-5f

typedef unsigned int u32;
typedef unsigned short u16;
typedef __attribute__((ext_vector_type(4))) u32 u32x4;
typedef __attribute__((ext_vector_type(4))) float f32x4;
typedef __attribute__((ext_vector_type(8))) __bf16 bf16x8;

__device__ __forceinline__ u16 f2bf(float f) {           // native RNE cvt
  return __builtin_bit_cast(u16, (__bf16)f);
}
__device__ __forceinline__ int sx6(int s) { return (s ^ (s >> 3)) & 7; }
__device__ __forceinline__ bf16x8 ldf(const u16* p) {
  return __builtin_bit_cast(bf16x8, *(const u32x4*)p);
}
__device__ __forceinline__ bf16x8 bcv(u32x4 v) { return __builtin_bit_cast(bf16x8, v); }
__device__ __forceinline__ float bflo(u32 p) { return __builtin_bit_cast(float, p << 16); }
__device__ __forceinline__ float bfhi(u32 p) { return __builtin_bit_cast(float, p & 0xffff0000u); }

__device__ __forceinline__ void gld16(u16* lds, const u16* g) {
  __builtin_amdgcn_global_load_lds(
      (const __attribute__((address_space(1))) u32*)g,
      (__attribute__((address_space(3))) u32*)lds, 16, 0, 0);
}
// barrier that does NOT drain vmcnt (keeps DMA/prefetch in flight)
__device__ __forceinline__ void barrier_lgkm() {
  asm volatile("s_waitcnt lgkmcnt(0)" ::: "memory");
  __builtin_amdgcn_sched_barrier(0);
  __builtin_amdgcn_s_barrier();
  __builtin_amdgcn_sched_barrier(0);
}
// full barrier (end of chunk: DMA must have landed)
__device__ __forceinline__ void barrier_all() {
  asm volatile("s_waitcnt vmcnt(0) lgkmcnt(0)" ::: "memory");
  __builtin_amdgcn_sched_barrier(0);
  __builtin_amdgcn_s_barrier();
  __builtin_amdgcn_sched_barrier(0);
}

// ---------------------------------------------------------------------------
// K1: x_act = tanh(x) -> kbs bf16, pre-swizzled rows:
//     kbs[row*512 + (k ^ (sx6(row&63)<<3))]
// ---------------------------------------------------------------------------
__global__ __launch_bounds__(256) void k_tanh(const float* __restrict__ x,
                                              u16* __restrict__ kbs) {
  int row  = blockIdx.x * 4 + (threadIdx.x >> 6);
  int lane = threadIdx.x & 63;
  const float* xr = x + (size_t)row * DD + lane * 8;
  float4 a = *(const float4*)xr;
  float4 b = *(const float4*)(xr + 4);
  float v[8] = {a.x, a.y, a.z, a.w, b.x, b.y, b.z, b.w};
  u32x4 pk;
#pragma unroll
  for (int j = 0; j < 4; ++j) {
    u16 h0 = f2bf(tanhf(v[2 * j]));
    u16 h1 = f2bf(tanhf(v[2 * j + 1]));
    pk[j] = (u32)h0 | ((u32)h1 << 16);
  }
  int s = row & 63;
  int k0 = (lane * 8) ^ (sx6(s) << 3);
  *(u32x4*)(kbs + (size_t)row * DD + k0) = pk;
}

// ---------------------------------------------------------------------------
// K1b: W -> bf16 (row-major)
// ---------------------------------------------------------------------------
__global__ __launch_bounds__(256) void k_cvtW(const float* __restrict__ W,
                                              u16* __restrict__ wbb) {
  int idx = (blockIdx.x * 256 + threadIdx.x) * 8;
  float4 a = *(const float4*)(W + idx);
  float4 b = *(const float4*)(W + idx + 4);
  float v[8] = {a.x, a.y, a.z, a.w, b.x, b.y, b.z, b.w};
  u32x4 pk;
#pragma unroll
  for (int j = 0; j < 4; ++j)
    pk[j] = (u32)f2bf(v[2 * j]) | ((u32)f2bf(v[2 * j + 1]) << 16);
  *(u32x4*)(wbb + idx) = pk;
}

// ---------------------------------------------------------------------------
// K2: per-(b,chunk) prep from bf16 kbs.
//   Outputs (bf16): tbb = beta*T ; tcb = -beta*T[s][r]*lam^{r+1} ;
//   mtb[s][r] = lam^{s-r}G[s][r] (r<s), G[s][s] (r==s), 0 else;
//   kbt = K^T pre-swizzled: kbt[k*64 + (s ^ (sx6(k)<<3))].
// ---------------------------------------------------------------------------
__global__ __launch_bounds__(256) void k_prep(const u16* __restrict__ kbs,
                                              const float* __restrict__ eta_p,
                                              const float* __restrict__ ll_p,
                                              u16* __restrict__ tbb,
                                              u16* __restrict__ tcb,
                                              u16* __restrict__ mtb,
                                              u16* __restrict__ kbt) {
  __shared__ float Gl[64 * 64];
  __shared__ float Gs[64 * 64];
  __shared__ float Tl[64 * 64];
  __shared__ float Klp[64 * 64];
  __shared__ float pw[72];
  int bc = blockIdx.x;
  int b = bc >> 5, c = bc & 31;
  int tid = threadIdx.x;
  float beta = *eta_p;
  float lam = 1.f / (1.f + expf(-*ll_p));
  if (tid <= 64) pw[tid] = powf(lam, (float)tid);
#pragma unroll
  for (int i = 0; i < 16; ++i) Tl[tid + i * 256] = 0.f;  // zero (fixed-trip solve)
  const u16* Kg = kbs + (size_t)(b * LL + c * CC) * DD;
  u16* ktb = kbt + (size_t)bc * CC * DD;  // [512][64]
  int tq = tid >> 4, sq = tid & 15;
  float acc[4][4] = {};
  for (int sl = 0; sl < 8; ++sl) {
    __syncthreads();
    // stage 64x64 slice (bf16 -> fp32, swizzled)
#pragma unroll
    for (int i = 0; i < 2; ++i) {
      int e8 = tid + i * 256;
      int r = e8 >> 3;
      int kq8 = (e8 & 7) * 8;
      u32x4 pk = *(const u32x4*)(Kg + (size_t)r * DD + ((sl * 64 + kq8) ^ (sx6(r) << 3)));
      float4 f0 = make_float4(bflo(pk[0]), bfhi(pk[0]), bflo(pk[1]), bfhi(pk[1]));
      float4 f1 = make_float4(bflo(pk[2]), bfhi(pk[2]), bflo(pk[3]), bfhi(pk[3]));
      *(float4*)&Klp[r * 64 + (kq8 ^ ((r & 7) << 2))] = f0;
      *(float4*)&Klp[r * 64 + ((kq8 + 4) ^ ((r & 7) << 2))] = f1;
    }
    __syncthreads();
    // transpose-out -> kbt (coalesced u32x4 rows of K^T)
    {
      int kr = tid >> 2, s0 = (tid & 3) * 16;
      int kf = sl * 64 + kr;
      u32 pk[8];
#pragma unroll
      for (int j = 0; j < 16; ++j) {
        int s = s0 + j;
        float vv = Klp[s * 64 + ((kr & ~3) ^ ((s & 7) << 2)) + (kr & 3)];
        u16 h = f2bf(vv);
        if (j & 1) pk[j >> 1] |= ((u32)h << 16); else pk[j >> 1] = (u32)h;
      }
      int m = sx6(kf) << 3;
      *(u32x4*)(ktb + (size_t)kf * 64 + (s0 ^ m)) = (u32x4){pk[0], pk[1], pk[2], pk[3]};
      *(u32x4*)(ktb + (size_t)kf * 64 + ((s0 + 8) ^ m)) = (u32x4){pk[4], pk[5], pk[6], pk[7]};
    }
    // G partial accumulation
#pragma unroll
    for (int k4 = 0; k4 < 16; ++k4) {
      int k = k4 * 4;
      float4 ta[4], sa[4];
#pragma unroll
      for (int i = 0; i < 4; ++i) {
        int tr = tq + 16 * i;
        ta[i] = *(const float4*)&Klp[tr * 64 + (k ^ ((tr & 7) << 2))];
      }
#pragma unroll
      for (int j = 0; j < 4; ++j) {
        int sr = sq + 16 * j;
        sa[j] = *(const float4*)&Klp[sr * 64 + (k ^ ((sr & 7) << 2))];
      }
#pragma unroll
      for (int i = 0; i < 4; ++i)
#pragma unroll
        for (int j = 0; j < 4; ++j)
          acc[i][j] += ta[i].x * sa[j].x + ta[i].y * sa[j].y +
                       ta[i].z * sa[j].z + ta[i].w * sa[j].w;
    }
  }
  __syncthreads();
#pragma unroll
  for (int i = 0; i < 4; ++i)
#pragma unroll
    for (int j = 0; j < 4; ++j) Gl[(tq + 16 * i) * 64 + (sq + 16 * j)] = acc[i][j];
  __syncthreads();
  // pre-scaled strictly-lower coefficients (zero elsewhere -> fixed-trip solve)
#pragma unroll
  for (int i = 0; i < 16; ++i) {
    int idx = tid + i * 256;
    int t = idx >> 6, s = idx & 63;
    Gs[idx] = (s < t) ? beta * pw[t - s] * Gl[idx] : 0.f;
  }
  __syncthreads();
  // forward substitution, fixed 64-iteration inner loop (pipelines cleanly)
  if (tid < 64) {
    int j = tid;
    for (int t = 0; t < 64; ++t) {
      float a0 = 0.f, a1 = 0.f, a2 = 0.f, a3 = 0.f;
#pragma unroll
      for (int s4 = 0; s4 < 16; ++s4) {
        int s = s4 * 4;
        a0 = fmaf(Gs[t * 64 + s], Tl[s * 64 + j], a0);
        a1 = fmaf(Gs[t * 64 + s + 1], Tl[(s + 1) * 64 + j], a1);
        a2 = fmaf(Gs[t * 64 + s + 2], Tl[(s + 2) * 64 + j], a2);
        a3 = fmaf(Gs[t * 64 + s + 3], Tl[(s + 3) * 64 + j], a3);
      }
      Tl[t * 64 + j] = ((t == j) ? 1.f : 0.f) - ((a0 + a1) + (a2 + a3));
    }
  }
  __syncthreads();
  u16* tb = tbb + (size_t)bc * 64 * 64;
  u16* tc = tcb + (size_t)bc * 64 * 64;
  u16* mt = mtb + (size_t)bc * 64 * 64;
#pragma unroll
  for (int i = 0; i < 16; ++i) {
    int idx = tid + i * 256;
    int s = idx >> 6, r = idx & 63;
    float tv = Tl[s * 64 + r];
    tb[idx] = f2bf(beta * tv);
    tc[idx] = f2bf(-(beta * tv * pw[r + 1]));
    mt[idx] = f2bf((r < s) ? pw[s - r] * Gl[s * 64 + r]
                           : ((r == s) ? Gl[s * 64 + r] : 0.f));
  }
}

// ---------------------------------------------------------------------------
// K3: MFMA chunked scan. WG = (b, v-block of 8). 256 thr (4 waves), 1 WG/CU.
//   V: V^T = W.K^T   A: U^T = S^T.K^T   B: W^T = V^T.Tb^T + U^T.(-Tc)^T
//   C: O^T = diag(lam^{s+1})U^T + W^T.Mt^T ; y = V+O
//   D: S^T = lam^64 S^T + Wsc^T.K   (B-frags direct from global kbt)
// K double-buffered via global_load_lds; mid-chunk barriers keep vmcnt alive.
// ---------------------------------------------------------------------------
__global__ __launch_bounds__(256, 1) void k_scan4(const u16* __restrict__ kbs,
                                                  const u16* __restrict__ kbt,
                                                  const u16* __restrict__ wbb,
                                                  const u16* __restrict__ tbb,
                                                  const u16* __restrict__ tcb,
                                                  const u16* __restrict__ mtb,
                                                  const float* __restrict__ ll_p,
                                                  float* __restrict__ y) {
  __shared__ __align__(16) u16 Kl[2][CC * DD];  // 2 x 64 KB pre-swizzled K
  __shared__ __align__(16) u16 Sb[16 * DD];     // bf16 state copy
  __shared__ __align__(16) u16 Vt[16 * 64];
  __shared__ __align__(16) u16 Ut[16 * 64];
  __shared__ __align__(16) u16 Wt[16 * 64];
  __shared__ __align__(16) u16 Ws[16 * 64];
  __shared__ float pwl[72];

  int b = blockIdx.x >> 6;
  int vb = blockIdx.x & 63;
  int v0 = vb * VB;
  int tid = threadIdx.x;
  int wid = tid >> 6, lane = tid & 63;
  int lo = lane & 15, hi = lane >> 4;

  float lam = 1.f / (1.f + expf(-*ll_p));
  if (tid <= 64) pwl[tid] = powf(lam, (float)tid);
  {
    u32x4 z = {0u, 0u, 0u, 0u};
#pragma unroll
    for (int i = 0; i < 4; ++i) *((u32x4*)Sb + tid + i * 256) = z;
    if (tid < 128) {
      *((u32x4*)Vt + tid) = z;
      *((u32x4*)Ut + tid) = z;
      *((u32x4*)Wt + tid) = z;
      *((u32x4*)Ws + tid) = z;
    }
  }
  const u16* kb_b = kbs + (size_t)b * LL * DD;
  // prologue: DMA chunk 0
#pragma unroll
  for (int i = 0; i < 16; ++i)
    gld16(Kl[0] + (size_t)(i * 256 + wid * 64) * 8,
          kb_b + (size_t)(i * 256 + wid * 64 + lane) * 8);
  // W A-fragments (chunk-invariant, regs)
  u32x4 wf[16];
#pragma unroll
  for (int k = 0; k < 16; ++k)
    wf[k] = *(const u32x4*)(wbb + (size_t)((v0 + lo) & 511) * DD + hi * 8 + k * 32);

  f32x4 Sa[8];
#pragma unroll
  for (int t = 0; t < 8; ++t) Sa[t] = (f32x4){0.f, 0.f, 0.f, 0.f};
  barrier_all();

  int sidx = 16 * wid + lo;
  int mK = sx6(sidx) << 3;
  int mLo = sx6(lo) << 3;
  float lam64 = pwl[64];
  float csc = pwl[sidx + 1];
  float dsc = pwl[63 - sidx];
  float* yb = y + (size_t)b * LL * DD;

  for (int c = 0; c < NC; ++c) {
    const u16* Kc = Kl[c & 1];
    // --- chunk-top prefetches (global; survive mid-chunk barriers) ---
    const u16* ktc = kbt + (size_t)(b * NC + c) * CC * DD;
    u32x4 kt0[8], kt1[8];
#pragma unroll
    for (int t = 0; t < 8; ++t) {
      int k = 16 * (8 * wid + t) + lo;
      const u16* rowp = ktc + (size_t)k * 64;
      int m = sx6(k) << 3;
      kt0[t] = *(const u32x4*)(rowp + ((8 * hi) ^ m));
      kt1[t] = *(const u32x4*)(rowp + ((8 * hi + 32) ^ m));
    }
    if (c + 1 < NC) {
      const u16* src = kb_b + (size_t)(c + 1) * CC * DD;
      u16* dbuf = Kl[(c + 1) & 1];
#pragma unroll
      for (int i = 0; i < 16; ++i)
        gld16(dbuf + (size_t)(i * 256 + wid * 64) * 8,
              src + (size_t)(i * 256 + wid * 64 + lane) * 8);
    }
    size_t tbase = ((size_t)(b * NC + c) * 64 + sidx) * 64 + hi * 8;
    u32x4 tb0 = *(const u32x4*)(tbb + tbase);
    u32x4 tb1 = *(const u32x4*)(tbb + tbase + 32);
    u32x4 tc0 = *(const u32x4*)(tcb + tbase);
    u32x4 tc1 = *(const u32x4*)(tcb + tbase + 32);
    u32x4 mt0 = *(const u32x4*)(mtb + tbase);
    u32x4 mt1 = *(const u32x4*)(mtb + tbase + 32);

    // ---- phases V + A ----
    f32x4 Va = {0.f, 0.f, 0.f, 0.f};
    f32x4 Ua = {0.f, 0.f, 0.f, 0.f};
#pragma unroll
    for (int k = 0; k < 16; ++k) {
      int col = hi * 8 + k * 32;
      bf16x8 kB = ldf(Kc + sidx * DD + (col ^ mK));
      bf16x8 sA = ldf(Sb + lo * DD + (col ^ mLo));
      Va = __builtin_amdgcn_mfma_f32_16x16x32_bf16(bcv(wf[k]), kB, Va, 0, 0, 0);
      Ua = __builtin_amdgcn_mfma_f32_16x16x32_bf16(sA, kB, Ua, 0, 0, 0);
    }
    if (hi < 2) {
#pragma unroll
      for (int r = 0; r < 4; ++r) {
        int v = 4 * hi + r;
        int idx = v * 64 + (sidx ^ (sx6(v) << 3));
        Vt[idx] = f2bf(Va[r]);
        Ut[idx] = f2bf(Ua[r]);
      }
    }
    barrier_lgkm();
    // ---- phase B ----
    f32x4 Wa = {0.f, 0.f, 0.f, 0.f};
    {
      bf16x8 vf0 = ldf(Vt + lo * 64 + ((hi * 8) ^ mLo));
      bf16x8 vf1 = ldf(Vt + lo * 64 + ((hi * 8 + 32) ^ mLo));
      bf16x8 uf0 = ldf(Ut + lo * 64 + ((hi * 8) ^ mLo));
      bf16x8 uf1 = ldf(Ut + lo * 64 + ((hi * 8 + 32) ^ mLo));
      Wa = __builtin_amdgcn_mfma_f32_16x16x32_bf16(vf0, bcv(tb0), Wa, 0, 0, 0);
      Wa = __builtin_amdgcn_mfma_f32_16x16x32_bf16(vf1, bcv(tb1), Wa, 0, 0, 0);
      Wa = __builtin_amdgcn_mfma_f32_16x16x32_bf16(uf0, bcv(tc0), Wa, 0, 0, 0);
      Wa = __builtin_amdgcn_mfma_f32_16x16x32_bf16(uf1, bcv(tc1), Wa, 0, 0, 0);
    }
    if (hi < 2) {
#pragma unroll
      for (int r = 0; r < 4; ++r) {
        int v = 4 * hi + r;
        int idx = v * 64 + (sidx ^ (sx6(v) << 3));
        Wt[idx] = f2bf(Wa[r]);
        Ws[idx] = f2bf(Wa[r] * dsc);
      }
    }
    barrier_lgkm();
    // ---- phase C ----
    f32x4 Oa = Ua * csc;
    {
      bf16x8 wf0 = ldf(Wt + lo * 64 + ((hi * 8) ^ mLo));
      bf16x8 wf1 = ldf(Wt + lo * 64 + ((hi * 8 + 32) ^ mLo));
      Oa = __builtin_amdgcn_mfma_f32_16x16x32_bf16(wf0, bcv(mt0), Oa, 0, 0, 0);
      Oa = __builtin_amdgcn_mfma_f32_16x16x32_bf16(wf1, bcv(mt1), Oa, 0, 0, 0);
    }
    if (hi < 2) {
      float4 yo = make_float4(Va[0] + Oa[0], Va[1] + Oa[1],
                              Va[2] + Oa[2], Va[3] + Oa[3]);
      *(float4*)(yb + (size_t)(c * CC + sidx) * DD + v0 + 4 * hi) = yo;
    }
    // ---- phase D ----
    {
      bf16x8 ws0 = ldf(Ws + lo * 64 + ((hi * 8) ^ mLo));
      bf16x8 ws1 = ldf(Ws + lo * 64 + ((hi * 8 + 32) ^ mLo));
#pragma unroll
      for (int t = 0; t < 8; ++t) {
        f32x4 acc = Sa[t] * lam64;
        acc = __builtin_amdgcn_mfma_f32_16x16x32_bf16(ws0, bcv(kt0[t]), acc, 0, 0, 0);
        acc = __builtin_amdgcn_mfma_f32_16x16x32_bf16(ws1, bcv(kt1[t]), acc, 0, 0, 0);
        Sa[t] = acc;
      }
      if (hi < 2) {
#pragma unroll
        for (int t = 0; t < 8; ++t) {
          int kc = 16 * (8 * wid + t) + lo;
#pragma unroll
          for (int r = 0; r < 4; ++r) {
            int v = 4 * hi + r;
            Sb[v * DD + (kc ^ (sx6(v) << 3))] = f2bf(Sa[t][r]);
          }
        }
      }
    }
    barrier_all();  // DMA landed + Sb visible for next chunk
  }
}

// ---------------------------------------------------------------------------
// K4: LayerNorm in-place on d_out.
// ---------------------------------------------------------------------------
__global__ __launch_bounds__(256) void k_ln(float* __restrict__ y,
                                            const float* __restrict__ gamma,
                                            const float* __restrict__ lbeta) {
  int row = blockIdx.x * 4 + (threadIdx.x >> 6);
  int lane = threadIdx.x & 63;
  float* yr = y + (size_t)row * DD + lane * 8;
  float4 a = *(const float4*)yr;
  float4 b = *(const float4*)(yr + 4);
  float v[8] = {a.x, a.y, a.z, a.w, b.x, b.y, b.z, b.w};
  float s = 0.f, ss = 0.f;
#pragma unroll
  for (int j = 0; j < 8; ++j) {
    s += v[j];
    ss = fmaf(v[j], v[j], ss);
  }
#pragma unroll
  for (int m = 1; m < 64; m <<= 1) {
    s += __shfl_xor(s, m, 64);
    ss += __shfl_xor(ss, m, 64);
  }
  float mu = s * (1.f / DD);
  float var = ss * (1.f / DD) - mu * mu;
  float inv = rsqrtf(var + EPSF);
  const float* gp = gamma + lane * 8;
  const float* bp = lbeta + lane * 8;
  float4 g0 = *(const float4*)gp;
  float4 g1 = *(const float4*)(gp + 4);
  float4 b0 = *(const float4*)bp;
  float4 b1 = *(const float4*)(bp + 4);
  float g[8] = {g0.x, g0.y, g0.z, g0.w, g1.x, g1.y, g1.z, g1.w};
  float bb[8] = {b0.x, b0.y, b0.z, b0.w, b1.x, b1.y, b1.z, b1.w};
#pragma unroll
  for (int j = 0; j < 8; ++j) v[j] = (v[j] - mu) * inv * g[j] + bb[j];
  *(float4*)yr = make_float4(v[0], v[1], v[2], v[3]);
  *(float4*)(yr + 4) = make_float4(v[4], v[5], v[6], v[7]);
}

// ---------------------------------------------------------------------------
extern "C" void kernel_launch(void* const* d_in, const int* in_sizes, int n_in,
                              void* d_out, int out_size, void* d_ws, size_t ws_size,
                              hipStream_t stream) {
  const float* x     = (const float*)d_in[0];
  const float* W     = (const float*)d_in[1];
  const float* eta   = (const float*)d_in[2];
  const float* ll    = (const float*)d_in[3];
  const float* gamma = (const float*)d_in[4];
  const float* lbeta = (const float*)d_in[5];
  float* out = (float*)d_out;

  // ws (u16): kbs 8MB | kbt 8MB | wbb 0.5MB | tbb/tcb/mtb 1MB each  (~20.5MB)
  u16* kbs = (u16*)d_ws;
  u16* kbt = kbs + (size_t)BB * LL * DD;
  u16* wbb = kbt + (size_t)BB * LL * DD;
  u16* tbb = wbb + (size_t)DD * DD;
  u16* tcb = tbb + (size_t)BB * NC * 64 * 64;
  u16* mtb = tcb + (size_t)BB * NC * 64 * 64;

  k_tanh<<<2048, 256, 0, stream>>>(x, kbs);
  k_cvtW<<<128, 256, 0, stream>>>(W, wbb);
  k_prep<<<BB * NC, 256, 0, stream>>>(kbs, eta, ll, tbb, tcb, mtb, kbt);
  k_scan4<<<256, 256, 0, stream>>>(kbs, kbt, wbb, tbb, tcb, mtb, ll, out);
  k_ln<<<2048, 256, 0, stream>>>(out, gamma, lbeta);
}

// Round 6
// 174.339 us; speedup vs baseline: 6.6535x; 1.1942x over previous
//
#include <hip/hip_runtime.h>
#include <math.h>

#define BB 4
#define LL 2048
#define DD 512
#define CC 64      // chunk length
#define NC 32      // number of chunks
#define VB 8       // v-columns owned per workgroup
#define EPSF 1e-5f

typedef unsigned int u32;
typedef unsigned short u16;
typedef __attribute__((ext_vector_type(4))) u32 u32x4;
typedef __attribute__((ext_vector_type(4))) float f32x4;
typedef __attribute__((ext_vector_type(8))) __bf16 bf16x8;

__device__ __forceinline__ u16 f2bf(float f) {           // native RNE cvt
  return __builtin_bit_cast(u16, (__bf16)f);
}
__device__ __forceinline__ int sx6(int s) { return (s ^ (s >> 3)) & 7; }
__device__ __forceinline__ bf16x8 ldf(const u16* p) {
  return __builtin_bit_cast(bf16x8, *(const u32x4*)p);
}
__device__ __forceinline__ bf16x8 bcv(u32x4 v) { return __builtin_bit_cast(bf16x8, v); }

__device__ __forceinline__ void gld16(u16* lds, const u16* g) {
  __builtin_amdgcn_global_load_lds(
      (const __attribute__((address_space(1))) u32*)g,
      (__attribute__((address_space(3))) u32*)lds, 16, 0, 0);
}
// barrier that drains only LDS (keeps global loads in flight)
__device__ __forceinline__ void barrier_lgkm() {
  asm volatile("s_waitcnt lgkmcnt(0)" ::: "memory");
  __builtin_amdgcn_sched_barrier(0);
  __builtin_amdgcn_s_barrier();
  __builtin_amdgcn_sched_barrier(0);
}
__device__ __forceinline__ void barrier_all() {
  asm volatile("s_waitcnt vmcnt(0) lgkmcnt(0)" ::: "memory");
  __builtin_amdgcn_sched_barrier(0);
  __builtin_amdgcn_s_barrier();
  __builtin_amdgcn_sched_barrier(0);
}

// ---------------------------------------------------------------------------
// K1: x_act = tanh(x) -> kbs bf16, pre-swizzled rows:
//     kbs[row*512 + (k ^ (sx6(row&63)<<3))]
// ---------------------------------------------------------------------------
__global__ __launch_bounds__(256) void k_tanh(const float* __restrict__ x,
                                              u16* __restrict__ kbs) {
  int row  = blockIdx.x * 4 + (threadIdx.x >> 6);
  int lane = threadIdx.x & 63;
  const float* xr = x + (size_t)row * DD + lane * 8;
  float4 a = *(const float4*)xr;
  float4 b = *(const float4*)(xr + 4);
  float v[8] = {a.x, a.y, a.z, a.w, b.x, b.y, b.z, b.w};
  u32x4 pk;
#pragma unroll
  for (int j = 0; j < 4; ++j) {
    u16 h0 = f2bf(tanhf(v[2 * j]));
    u16 h1 = f2bf(tanhf(v[2 * j + 1]));
    pk[j] = (u32)h0 | ((u32)h1 << 16);
  }
  int s = row & 63;
  int k0 = (lane * 8) ^ (sx6(s) << 3);
  *(u32x4*)(kbs + (size_t)row * DD + k0) = pk;
}

// ---------------------------------------------------------------------------
// K1b: W -> bf16 (row-major)
// ---------------------------------------------------------------------------
__global__ __launch_bounds__(256) void k_cvtW(const float* __restrict__ W,
                                              u16* __restrict__ wbb) {
  int idx = (blockIdx.x * 256 + threadIdx.x) * 8;
  float4 a = *(const float4*)(W + idx);
  float4 b = *(const float4*)(W + idx + 4);
  float v[8] = {a.x, a.y, a.z, a.w, b.x, b.y, b.z, b.w};
  u32x4 pk;
#pragma unroll
  for (int j = 0; j < 4; ++j)
    pk[j] = (u32)f2bf(v[2 * j]) | ((u32)f2bf(v[2 * j + 1]) << 16);
  *(u32x4*)(wbb + idx) = pk;
}

// ---------------------------------------------------------------------------
// K2: per-(b,chunk) prep, rebuilt:
//   G = K K^T via MFMA (bf16 in / fp32 acc), 4 waves x 4 tiles each.
//   T = (I+A)^{-1} forward substitution: 4 lanes per column, all 4 waves.
//   Outputs (bf16): tbb = beta*T ; tcb = -beta*T[s][r]*lam^{r+1} ;
//   mtb[s][r] = lam^{s-r}G[s][r] (r<s), G[s][s] (r==s), 0 else;
//   kbt = K^T pre-swizzled: kbt[k*64 + (s ^ (sx6(k)<<3))].
// ---------------------------------------------------------------------------
__global__ __launch_bounds__(256) void k_prep2(const u16* __restrict__ kbs,
                                               const float* __restrict__ eta_p,
                                               const float* __restrict__ ll_p,
                                               u16* __restrict__ tbb,
                                               u16* __restrict__ tcb,
                                               u16* __restrict__ mtb,
                                               u16* __restrict__ kbt) {
  __shared__ __align__(16) u16 Kl[CC * DD];   // 64 KB bf16 chunk, pre-swizzled
  __shared__ float Gl[64 * 64];               // 16 KB
  __shared__ float Gs[64 * 64];               // 16 KB
  __shared__ float Tl[64 * 65];               // 16.25 KB (pad 65 vs bank aliasing)
  __shared__ float pw[72];
  int bc = blockIdx.x;
  int b = bc >> 5, c = bc & 31;
  int tid = threadIdx.x;
  int wid = tid >> 6, lane = tid & 63;
  int lo = lane & 15, hi = lane >> 4;
  float beta = *eta_p;
  float lam = 1.f / (1.f + expf(-*ll_p));
  if (tid <= 64) pw[tid] = powf(lam, (float)tid);
  for (int i = tid; i < 64 * 65; i += 256) Tl[i] = 0.f;
  const u16* Kg = kbs + (size_t)(b * LL + c * CC) * DD;
#pragma unroll
  for (int i = 0; i < 16; ++i)
    gld16(Kl + (size_t)(i * 256 + tid) * 8, Kg + (size_t)(i * 256 + tid) * 8);
  __syncthreads();
  // ---- G = K K^T via MFMA: wave w owns t-block [16w,16w+16), 4 s-tiles ----
  {
    f32x4 acc[4] = {{0.f,0.f,0.f,0.f},{0.f,0.f,0.f,0.f},{0.f,0.f,0.f,0.f},{0.f,0.f,0.f,0.f}};
    int t = 16 * wid + lo;
    int mT = sx6(t) << 3;
#pragma unroll
    for (int kq = 0; kq < 16; ++kq) {
      int col = hi * 8 + kq * 32;
      bf16x8 aF = ldf(Kl + t * DD + (col ^ mT));
#pragma unroll
      for (int sb = 0; sb < 4; ++sb) {
        int s = 16 * sb + lo;
        bf16x8 bF = ldf(Kl + s * DD + (col ^ (sx6(s) << 3)));
        acc[sb] = __builtin_amdgcn_mfma_f32_16x16x32_bf16(aF, bF, acc[sb], 0, 0, 0);
      }
    }
#pragma unroll
    for (int sb = 0; sb < 4; ++sb)
#pragma unroll
      for (int r = 0; r < 4; ++r)
        Gl[(16 * wid + 4 * hi + r) * 64 + 16 * sb + lo] = acc[sb][r];
  }
  __syncthreads();
  // ---- pre-scaled strictly-lower coefficients ----
#pragma unroll
  for (int i = 0; i < 16; ++i) {
    int idx = tid + i * 256;
    int tq = idx >> 6, sq = idx & 63;
    Gs[idx] = (sq < tq) ? beta * pw[tq - sq] * Gl[idx] : 0.f;
  }
  __syncthreads();
  // ---- forward substitution: wave w col j=16w+jj, 4 lanes (q) split s ----
  {
    int q = hi;            // s-quarter [16q,16q+16)
    int j = 16 * wid + lo; // column
    for (int t = 0; t < 64; ++t) {
      float ps = 0.f;
#pragma unroll
      for (int i = 0; i < 16; ++i) {
        int s = 16 * q + i;
        ps = fmaf(Gs[t * 64 + s], Tl[s * 65 + j], ps);
      }
      ps += __shfl_xor(ps, 16, 64);
      ps += __shfl_xor(ps, 32, 64);
      if (q == 0) Tl[t * 65 + j] = ((t == j) ? 1.f : 0.f) - ps;
    }
  }
  __syncthreads();
  // ---- outputs ----
  u16* tb = tbb + (size_t)bc * 64 * 64;
  u16* tc = tcb + (size_t)bc * 64 * 64;
  u16* mt = mtb + (size_t)bc * 64 * 64;
#pragma unroll
  for (int i = 0; i < 16; ++i) {
    int idx = tid + i * 256;
    int s = idx >> 6, r = idx & 63;
    float tv = Tl[s * 65 + r];
    tb[idx] = f2bf(beta * tv);
    tc[idx] = f2bf(-(beta * tv * pw[r + 1]));
    mt[idx] = f2bf((r < s) ? pw[s - r] * Gl[s * 64 + r]
                           : ((r == s) ? Gl[s * 64 + r] : 0.f));
  }
  // ---- kbt = K^T, swizzled groups of 8 s per row k ----
  u16* ktb = kbt + (size_t)bc * CC * DD;
#pragma unroll
  for (int rr = 0; rr < 2; ++rr) {
    int k = rr * 256 + tid;
    int kbase = k & ~7, klo = k & 7;
    int mk = sx6(k) << 3;
#pragma unroll
    for (int g = 0; g < 8; ++g) {
      u32 w4[4];
#pragma unroll
      for (int p = 0; p < 4; ++p) {
        int s0 = g * 8 + 2 * p;
        u16 e0 = Kl[s0 * DD + (kbase ^ (sx6(s0) << 3)) + klo];
        u16 e1 = Kl[(s0 + 1) * DD + (kbase ^ (sx6(s0 + 1) << 3)) + klo];
        w4[p] = (u32)e0 | ((u32)e1 << 16);
      }
      *(u32x4*)(ktb + (size_t)k * 64 + ((8 * g) ^ mk)) = (u32x4){w4[0], w4[1], w4[2], w4[3]};
    }
  }
}

// ---------------------------------------------------------------------------
// K3: MFMA chunked scan, latency-optimized.
//   Single-buffer Kl + register staging (T14). No vmcnt drains in the loop:
//   all global ops are register loads (compiler-counted waits). kt/Tb/Tc/Mt
//   for c+1 loaded at chunk END (full-chunk latency cover). Split acc chains.
// ---------------------------------------------------------------------------
__global__ __launch_bounds__(256, 1) void k_scan5(const u16* __restrict__ kbs,
                                                  const u16* __restrict__ kbt,
                                                  const u16* __restrict__ wbb,
                                                  const u16* __restrict__ tbb,
                                                  const u16* __restrict__ tcb,
                                                  const u16* __restrict__ mtb,
                                                  const float* __restrict__ ll_p,
                                                  float* __restrict__ y) {
  __shared__ __align__(16) u16 Kl[CC * DD];     // 64 KB (single buffer)
  __shared__ __align__(16) u16 Sb[16 * DD];     // 16 KB bf16 state copy
  __shared__ __align__(16) u16 Vt[16 * 64];
  __shared__ __align__(16) u16 Ut[16 * 64];
  __shared__ __align__(16) u16 Wt[16 * 64];
  __shared__ __align__(16) u16 Ws[16 * 64];

  int b = blockIdx.x >> 6;
  int vb = blockIdx.x & 63;
  int v0 = vb * VB;
  int tid = threadIdx.x;
  int wid = tid >> 6, lane = tid & 63;
  int lo = lane & 15, hi = lane >> 4;

  float lam = 1.f / (1.f + expf(-*ll_p));
  int sidx = 16 * wid + lo;
  int mK = sx6(sidx) << 3;
  int mLo = sx6(lo) << 3;
  float lam64 = powf(lam, 64.f);
  float csc = powf(lam, (float)(sidx + 1));
  float dsc = powf(lam, (float)(63 - sidx));

  {
    u32x4 z = {0u, 0u, 0u, 0u};
#pragma unroll
    for (int i = 0; i < 4; ++i) *((u32x4*)Sb + tid + i * 256) = z;
    if (tid < 128) {
      *((u32x4*)Vt + tid) = z;
      *((u32x4*)Ut + tid) = z;
      *((u32x4*)Wt + tid) = z;
      *((u32x4*)Ws + tid) = z;
    }
  }
  const u16* kb_b = kbs + (size_t)b * LL * DD;
  float* yb = y + (size_t)b * LL * DD;

  // W A-fragments (chunk-invariant)
  u32x4 wf[16];
#pragma unroll
  for (int k = 0; k < 16; ++k)
    wf[k] = *(const u32x4*)(wbb + (size_t)((v0 + lo) & 511) * DD + hi * 8 + k * 32);

  // ---- prologue: stage chunk 0 + frames for chunk 0 ----
  u32x4 sreg[16];
#pragma unroll
  for (int i = 0; i < 16; ++i)
    sreg[i] = *(const u32x4*)(kb_b + (size_t)(i * 256 + tid) * 8);
  u32x4 kt0[8], kt1[8], tb0, tb1, tc0, tc1, mt0, mt1;
  {
    const u16* ktc = kbt + (size_t)(b * NC + 0) * CC * DD;
#pragma unroll
    for (int t = 0; t < 8; ++t) {
      int k = 16 * (8 * wid + t) + lo;
      const u16* rowp = ktc + (size_t)k * 64;
      int m = sx6(k) << 3;
      kt0[t] = *(const u32x4*)(rowp + ((8 * hi) ^ m));
      kt1[t] = *(const u32x4*)(rowp + ((8 * hi + 32) ^ m));
    }
    size_t tbase = ((size_t)(b * NC + 0) * 64 + sidx) * 64 + hi * 8;
    tb0 = *(const u32x4*)(tbb + tbase);
    tb1 = *(const u32x4*)(tbb + tbase + 32);
    tc0 = *(const u32x4*)(tcb + tbase);
    tc1 = *(const u32x4*)(tcb + tbase + 32);
    mt0 = *(const u32x4*)(mtb + tbase);
    mt1 = *(const u32x4*)(mtb + tbase + 32);
  }
#pragma unroll
  for (int i = 0; i < 16; ++i)
    *(u32x4*)(Kl + (size_t)(i * 256 + tid) * 8) = sreg[i];

  f32x4 Sa[8];
#pragma unroll
  for (int t = 0; t < 8; ++t) Sa[t] = (f32x4){0.f, 0.f, 0.f, 0.f};
  barrier_all();

  for (int c = 0; c < NC; ++c) {
    // issue stage loads for c+1 at chunk top (land by stage-write after bar1)
    if (c + 1 < NC) {
      const u16* src = kb_b + (size_t)(c + 1) * CC * DD;
#pragma unroll
      for (int i = 0; i < 16; ++i)
        sreg[i] = *(const u32x4*)(src + (size_t)(i * 256 + tid) * 8);
    }
    // ---- phases V + A (split accumulator chains) ----
    f32x4 Va0 = {0.f,0.f,0.f,0.f}, Va1 = {0.f,0.f,0.f,0.f};
    f32x4 Ua0 = {0.f,0.f,0.f,0.f}, Ua1 = {0.f,0.f,0.f,0.f};
#pragma unroll
    for (int k = 0; k < 16; ++k) {
      int col = hi * 8 + k * 32;
      bf16x8 kB = ldf(Kl + sidx * DD + (col ^ mK));
      bf16x8 sA = ldf(Sb + lo * DD + (col ^ mLo));
      if (k & 1) {
        Va1 = __builtin_amdgcn_mfma_f32_16x16x32_bf16(bcv(wf[k]), kB, Va1, 0, 0, 0);
        Ua1 = __builtin_amdgcn_mfma_f32_16x16x32_bf16(sA, kB, Ua1, 0, 0, 0);
      } else {
        Va0 = __builtin_amdgcn_mfma_f32_16x16x32_bf16(bcv(wf[k]), kB, Va0, 0, 0, 0);
        Ua0 = __builtin_amdgcn_mfma_f32_16x16x32_bf16(sA, kB, Ua0, 0, 0, 0);
      }
    }
    f32x4 Va = Va0 + Va1;
    f32x4 Ua = Ua0 + Ua1;
    if (hi < 2) {
#pragma unroll
      for (int r = 0; r < 4; ++r) {
        int v = 4 * hi + r;
        int idx = v * 64 + (sidx ^ (sx6(v) << 3));
        Vt[idx] = f2bf(Va[r]);
        Ut[idx] = f2bf(Ua[r]);
      }
    }
    barrier_lgkm();
    // stage-write c+1 into Kl (current chunk's Kl reads all done)
    if (c + 1 < NC) {
#pragma unroll
      for (int i = 0; i < 16; ++i)
        *(u32x4*)(Kl + (size_t)(i * 256 + tid) * 8) = sreg[i];
    }
    // ---- phase B (2 split chains) ----
    f32x4 Wa;
    {
      bf16x8 vf0 = ldf(Vt + lo * 64 + ((hi * 8) ^ mLo));
      bf16x8 vf1 = ldf(Vt + lo * 64 + ((hi * 8 + 32) ^ mLo));
      bf16x8 uf0 = ldf(Ut + lo * 64 + ((hi * 8) ^ mLo));
      bf16x8 uf1 = ldf(Ut + lo * 64 + ((hi * 8 + 32) ^ mLo));
      f32x4 Wa0 = {0.f,0.f,0.f,0.f}, Wa1 = {0.f,0.f,0.f,0.f};
      Wa0 = __builtin_amdgcn_mfma_f32_16x16x32_bf16(vf0, bcv(tb0), Wa0, 0, 0, 0);
      Wa1 = __builtin_amdgcn_mfma_f32_16x16x32_bf16(vf1, bcv(tb1), Wa1, 0, 0, 0);
      Wa0 = __builtin_amdgcn_mfma_f32_16x16x32_bf16(uf0, bcv(tc0), Wa0, 0, 0, 0);
      Wa1 = __builtin_amdgcn_mfma_f32_16x16x32_bf16(uf1, bcv(tc1), Wa1, 0, 0, 0);
      Wa = Wa0 + Wa1;
    }
    if (hi < 2) {
#pragma unroll
      for (int r = 0; r < 4; ++r) {
        int v = 4 * hi + r;
        int idx = v * 64 + (sidx ^ (sx6(v) << 3));
        Wt[idx] = f2bf(Wa[r]);
        Ws[idx] = f2bf(Wa[r] * dsc);
      }
    }
    barrier_lgkm();
    // ---- phase C ----
    f32x4 Oa = Ua * csc;
    {
      bf16x8 wff0 = ldf(Wt + lo * 64 + ((hi * 8) ^ mLo));
      bf16x8 wff1 = ldf(Wt + lo * 64 + ((hi * 8 + 32) ^ mLo));
      Oa = __builtin_amdgcn_mfma_f32_16x16x32_bf16(wff0, bcv(mt0), Oa, 0, 0, 0);
      Oa = __builtin_amdgcn_mfma_f32_16x16x32_bf16(wff1, bcv(mt1), Oa, 0, 0, 0);
    }
    if (hi < 2) {
      float4 yo = make_float4(Va[0] + Oa[0], Va[1] + Oa[1],
                              Va[2] + Oa[2], Va[3] + Oa[3]);
      *(float4*)(yb + (size_t)(c * CC + sidx) * DD + v0 + 4 * hi) = yo;
    }
    // ---- phase D ----
    {
      bf16x8 ws0 = ldf(Ws + lo * 64 + ((hi * 8) ^ mLo));
      bf16x8 ws1 = ldf(Ws + lo * 64 + ((hi * 8 + 32) ^ mLo));
#pragma unroll
      for (int t = 0; t < 8; ++t) {
        f32x4 acc = Sa[t] * lam64;
        acc = __builtin_amdgcn_mfma_f32_16x16x32_bf16(ws0, bcv(kt0[t]), acc, 0, 0, 0);
        acc = __builtin_amdgcn_mfma_f32_16x16x32_bf16(ws1, bcv(kt1[t]), acc, 0, 0, 0);
        Sa[t] = acc;
      }
      if (hi < 2) {
#pragma unroll
        for (int t = 0; t < 8; ++t) {
          int kc = 16 * (8 * wid + t) + lo;
#pragma unroll
          for (int r = 0; r < 4; ++r) {
            int v = 4 * hi + r;
            Sb[v * DD + (kc ^ (sx6(v) << 3))] = f2bf(Sa[t][r]);
          }
        }
      }
    }
    // ---- load frames for c+1 (full-chunk latency cover) ----
    if (c + 1 < NC) {
      const u16* ktc = kbt + (size_t)(b * NC + c + 1) * CC * DD;
#pragma unroll
      for (int t = 0; t < 8; ++t) {
        int k = 16 * (8 * wid + t) + lo;
        const u16* rowp = ktc + (size_t)k * 64;
        int m = sx6(k) << 3;
        kt0[t] = *(const u32x4*)(rowp + ((8 * hi) ^ m));
        kt1[t] = *(const u32x4*)(rowp + ((8 * hi + 32) ^ m));
      }
      size_t tbase = ((size_t)(b * NC + c + 1) * 64 + sidx) * 64 + hi * 8;
      tb0 = *(const u32x4*)(tbb + tbase);
      tb1 = *(const u32x4*)(tbb + tbase + 32);
      tc0 = *(const u32x4*)(tcb + tbase);
      tc1 = *(const u32x4*)(tcb + tbase + 32);
      mt0 = *(const u32x4*)(mtb + tbase);
      mt1 = *(const u32x4*)(mtb + tbase + 32);
    }
    barrier_lgkm();
  }
}

// ---------------------------------------------------------------------------
// K4: LayerNorm in-place on d_out.
// ---------------------------------------------------------------------------
__global__ __launch_bounds__(256) void k_ln(float* __restrict__ y,
                                            const float* __restrict__ gamma,
                                            const float* __restrict__ lbeta) {
  int row = blockIdx.x * 4 + (threadIdx.x >> 6);
  int lane = threadIdx.x & 63;
  float* yr = y + (size_t)row * DD + lane * 8;
  float4 a = *(const float4*)yr;
  float4 b = *(const float4*)(yr + 4);
  float v[8] = {a.x, a.y, a.z, a.w, b.x, b.y, b.z, b.w};
  float s = 0.f, ss = 0.f;
#pragma unroll
  for (int j = 0; j < 8; ++j) {
    s += v[j];
    ss = fmaf(v[j], v[j], ss);
  }
#pragma unroll
  for (int m = 1; m < 64; m <<= 1) {
    s += __shfl_xor(s, m, 64);
    ss += __shfl_xor(ss, m, 64);
  }
  float mu = s * (1.f / DD);
  float var = ss * (1.f / DD) - mu * mu;
  float inv = rsqrtf(var + EPSF);
  const float* gp = gamma + lane * 8;
  const float* bp = lbeta + lane * 8;
  float4 g0 = *(const float4*)gp;
  float4 g1 = *(const float4*)(gp + 4);
  float4 b0 = *(const float4*)bp;
  float4 b1 = *(const float4*)(bp + 4);
  float g[8] = {g0.x, g0.y, g0.z, g0.w, g1.x, g1.y, g1.z, g1.w};
  float bb[8] = {b0.x, b0.y, b0.z, b0.w, b1.x, b1.y, b1.z, b1.w};
#pragma unroll
  for (int j = 0; j < 8; ++j) v[j] = (v[j] - mu) * inv * g[j] + bb[j];
  *(float4*)yr = make_float4(v[0], v[1], v[2], v[3]);
  *(float4*)(yr + 4) = make_float4(v[4], v[5], v[6], v[7]);
}

// ---------------------------------------------------------------------------
extern "C" void kernel_launch(void* const* d_in, const int* in_sizes, int n_in,
                              void* d_out, int out_size, void* d_ws, size_t ws_size,
                              hipStream_t stream) {
  const float* x     = (const float*)d_in[0];
  const float* W     = (const float*)d_in[1];
  const float* eta   = (const float*)d_in[2];
  const float* ll    = (const float*)d_in[3];
  const float* gamma = (const float*)d_in[4];
  const float* lbeta = (const float*)d_in[5];
  float* out = (float*)d_out;

  // ws (u16): kbs 8MB | kbt 8MB | wbb 0.5MB | tbb/tcb/mtb 1MB each (~20.5MB)
  u16* kbs = (u16*)d_ws;
  u16* kbt = kbs + (size_t)BB * LL * DD;
  u16* wbb = kbt + (size_t)BB * LL * DD;
  u16* tbb = wbb + (size_t)DD * DD;
  u16* tcb = tbb + (size_t)BB * NC * 64 * 64;
  u16* mtb = tcb + (size_t)BB * NC * 64 * 64;

  k_tanh<<<2048, 256, 0, stream>>>(x, kbs);
  k_cvtW<<<128, 256, 0, stream>>>(W, wbb);
  k_prep2<<<BB * NC, 256, 0, stream>>>(kbs, eta, ll, tbb, tcb, mtb, kbt);
  k_scan5<<<256, 256, 0, stream>>>(kbs, kbt, wbb, tbb, tcb, mtb, ll, out);
  k_ln<<<2048, 256, 0, stream>>>(out, gamma, lbeta);
}

// Round 7
// 148.855 us; speedup vs baseline: 7.7926x; 1.1712x over previous
//
#include <hip/hip_runtime.h>
#include <math.h>

#define BB 4
#define LL 2048
#define DD 512
#define CC 64      // chunk length
#define NC 32      // number of chunks
#define VB 8       // v-columns owned per workgroup
#define EPSF 1e-5f

typedef unsigned int u32;
typedef unsigned short u16;
typedef __attribute__((ext_vector_type(4))) u32 u32x4;
typedef __attribute__((ext_vector_type(4))) float f32x4;
typedef __attribute__((ext_vector_type(8))) __bf16 bf16x8;

__device__ __forceinline__ u16 f2bf(float f) {           // native RNE cvt
  return __builtin_bit_cast(u16, (__bf16)f);
}
__device__ __forceinline__ int sx6(int s) { return (s ^ (s >> 3)) & 7; }
__device__ __forceinline__ bf16x8 ldf(const u16* p) {
  return __builtin_bit_cast(bf16x8, *(const u32x4*)p);
}
__device__ __forceinline__ bf16x8 bcv(u32x4 v) { return __builtin_bit_cast(bf16x8, v); }

__device__ __forceinline__ void gld16(u16* lds, const u16* g) {
  __builtin_amdgcn_global_load_lds(
      (const __attribute__((address_space(1))) u32*)g,
      (__attribute__((address_space(3))) u32*)lds, 16, 0, 0);
}
// barrier that drains only LDS (keeps global loads in flight)
__device__ __forceinline__ void barrier_lgkm() {
  asm volatile("s_waitcnt lgkmcnt(0)" ::: "memory");
  __builtin_amdgcn_sched_barrier(0);
  __builtin_amdgcn_s_barrier();
  __builtin_amdgcn_sched_barrier(0);
}
__device__ __forceinline__ void barrier_all() {
  asm volatile("s_waitcnt vmcnt(0) lgkmcnt(0)" ::: "memory");
  __builtin_amdgcn_sched_barrier(0);
  __builtin_amdgcn_s_barrier();
  __builtin_amdgcn_sched_barrier(0);
}

// ---------------------------------------------------------------------------
// K1: x_act = tanh(x) -> kbs bf16, pre-swizzled rows:
//     kbs[row*512 + (k ^ (sx6(row&63)<<3))]
// ---------------------------------------------------------------------------
__global__ __launch_bounds__(256) void k_tanh(const float* __restrict__ x,
                                              u16* __restrict__ kbs) {
  int row  = blockIdx.x * 4 + (threadIdx.x >> 6);
  int lane = threadIdx.x & 63;
  const float* xr = x + (size_t)row * DD + lane * 8;
  float4 a = *(const float4*)xr;
  float4 b = *(const float4*)(xr + 4);
  float v[8] = {a.x, a.y, a.z, a.w, b.x, b.y, b.z, b.w};
  u32x4 pk;
#pragma unroll
  for (int j = 0; j < 4; ++j) {
    u16 h0 = f2bf(tanhf(v[2 * j]));
    u16 h1 = f2bf(tanhf(v[2 * j + 1]));
    pk[j] = (u32)h0 | ((u32)h1 << 16);
  }
  int s = row & 63;
  int k0 = (lane * 8) ^ (sx6(s) << 3);
  *(u32x4*)(kbs + (size_t)row * DD + k0) = pk;
}

// ---------------------------------------------------------------------------
// K1b: W -> bf16 (row-major)
// ---------------------------------------------------------------------------
__global__ __launch_bounds__(256) void k_cvtW(const float* __restrict__ W,
                                              u16* __restrict__ wbb) {
  int idx = (blockIdx.x * 256 + threadIdx.x) * 8;
  float4 a = *(const float4*)(W + idx);
  float4 b = *(const float4*)(W + idx + 4);
  float v[8] = {a.x, a.y, a.z, a.w, b.x, b.y, b.z, b.w};
  u32x4 pk;
#pragma unroll
  for (int j = 0; j < 4; ++j)
    pk[j] = (u32)f2bf(v[2 * j]) | ((u32)f2bf(v[2 * j + 1]) << 16);
  *(u32x4*)(wbb + idx) = pk;
}

// ---------------------------------------------------------------------------
// K2: per-(b,chunk) prep (unchanged from R6):
//   G = K K^T via MFMA; T = (I+A)^{-1} forward substitution (4 lanes/col).
//   Outputs (bf16): tbb = beta*T ; tcb = -beta*T[s][r]*lam^{r+1} ;
//   mtb[s][r] = lam^{s-r}G[s][r] (r<s), G[s][s] (r==s), 0 else;
//   kbt = K^T pre-swizzled: kbt[k*64 + (s ^ (sx6(k)<<3))].
// ---------------------------------------------------------------------------
__global__ __launch_bounds__(256) void k_prep2(const u16* __restrict__ kbs,
                                               const float* __restrict__ eta_p,
                                               const float* __restrict__ ll_p,
                                               u16* __restrict__ tbb,
                                               u16* __restrict__ tcb,
                                               u16* __restrict__ mtb,
                                               u16* __restrict__ kbt) {
  __shared__ __align__(16) u16 Kl[CC * DD];
  __shared__ float Gl[64 * 64];
  __shared__ float Gs[64 * 64];
  __shared__ float Tl[64 * 65];
  __shared__ float pw[72];
  int bc = blockIdx.x;
  int b = bc >> 5, c = bc & 31;
  int tid = threadIdx.x;
  int wid = tid >> 6, lane = tid & 63;
  int lo = lane & 15, hi = lane >> 4;
  float beta = *eta_p;
  float lam = 1.f / (1.f + expf(-*ll_p));
  if (tid <= 64) pw[tid] = powf(lam, (float)tid);
  for (int i = tid; i < 64 * 65; i += 256) Tl[i] = 0.f;
  const u16* Kg = kbs + (size_t)(b * LL + c * CC) * DD;
#pragma unroll
  for (int i = 0; i < 16; ++i)
    gld16(Kl + (size_t)(i * 256 + tid) * 8, Kg + (size_t)(i * 256 + tid) * 8);
  __syncthreads();
  {
    f32x4 acc[4] = {{0.f,0.f,0.f,0.f},{0.f,0.f,0.f,0.f},{0.f,0.f,0.f,0.f},{0.f,0.f,0.f,0.f}};
    int t = 16 * wid + lo;
    int mT = sx6(t) << 3;
#pragma unroll
    for (int kq = 0; kq < 16; ++kq) {
      int col = hi * 8 + kq * 32;
      bf16x8 aF = ldf(Kl + t * DD + (col ^ mT));
#pragma unroll
      for (int sb = 0; sb < 4; ++sb) {
        int s = 16 * sb + lo;
        bf16x8 bF = ldf(Kl + s * DD + (col ^ (sx6(s) << 3)));
        acc[sb] = __builtin_amdgcn_mfma_f32_16x16x32_bf16(aF, bF, acc[sb], 0, 0, 0);
      }
    }
#pragma unroll
    for (int sb = 0; sb < 4; ++sb)
#pragma unroll
      for (int r = 0; r < 4; ++r)
        Gl[(16 * wid + 4 * hi + r) * 64 + 16 * sb + lo] = acc[sb][r];
  }
  __syncthreads();
#pragma unroll
  for (int i = 0; i < 16; ++i) {
    int idx = tid + i * 256;
    int tq = idx >> 6, sq = idx & 63;
    Gs[idx] = (sq < tq) ? beta * pw[tq - sq] * Gl[idx] : 0.f;
  }
  __syncthreads();
  {
    int q = hi;
    int j = 16 * wid + lo;
    for (int t = 0; t < 64; ++t) {
      float ps = 0.f;
#pragma unroll
      for (int i = 0; i < 16; ++i) {
        int s = 16 * q + i;
        ps = fmaf(Gs[t * 64 + s], Tl[s * 65 + j], ps);
      }
      ps += __shfl_xor(ps, 16, 64);
      ps += __shfl_xor(ps, 32, 64);
      if (q == 0) Tl[t * 65 + j] = ((t == j) ? 1.f : 0.f) - ps;
    }
  }
  __syncthreads();
  u16* tb = tbb + (size_t)bc * 64 * 64;
  u16* tc = tcb + (size_t)bc * 64 * 64;
  u16* mt = mtb + (size_t)bc * 64 * 64;
#pragma unroll
  for (int i = 0; i < 16; ++i) {
    int idx = tid + i * 256;
    int s = idx >> 6, r = idx & 63;
    float tv = Tl[s * 65 + r];
    tb[idx] = f2bf(beta * tv);
    tc[idx] = f2bf(-(beta * tv * pw[r + 1]));
    mt[idx] = f2bf((r < s) ? pw[s - r] * Gl[s * 64 + r]
                           : ((r == s) ? Gl[s * 64 + r] : 0.f));
  }
  u16* ktb = kbt + (size_t)bc * CC * DD;
#pragma unroll
  for (int rr = 0; rr < 2; ++rr) {
    int k = rr * 256 + tid;
    int kbase = k & ~7, klo = k & 7;
    int mk = sx6(k) << 3;
#pragma unroll
    for (int g = 0; g < 8; ++g) {
      u32 w4[4];
#pragma unroll
      for (int p = 0; p < 4; ++p) {
        int s0 = g * 8 + 2 * p;
        u16 e0 = Kl[s0 * DD + (kbase ^ (sx6(s0) << 3)) + klo];
        u16 e1 = Kl[(s0 + 1) * DD + (kbase ^ (sx6(s0 + 1) << 3)) + klo];
        w4[p] = (u32)e0 | ((u32)e1 << 16);
      }
      *(u32x4*)(ktb + (size_t)k * 64 + ((8 * g) ^ mk)) = (u32x4){w4[0], w4[1], w4[2], w4[3]};
    }
  }
}

// ---------------------------------------------------------------------------
// K3: MFMA chunked scan, 8 waves (512 thr) = 2 waves/SIMD, k-split.
//   Wave (wq,kh): kh-half of phases V/A; B on kh=0 while C on kh=1 (role
//   split across SIMD pair); D split 4/4 state tiles per kh.
// ---------------------------------------------------------------------------
__global__ __launch_bounds__(512, 2) void k_scan6(const u16* __restrict__ kbs,
                                                  const u16* __restrict__ kbt,
                                                  const u16* __restrict__ wbb,
                                                  const u16* __restrict__ tbb,
                                                  const u16* __restrict__ tcb,
                                                  const u16* __restrict__ mtb,
                                                  const float* __restrict__ ll_p,
                                                  float* __restrict__ y) {
  __shared__ __align__(16) u16 Kl[CC * DD];     // 64 KB
  __shared__ __align__(16) u16 Sb[16 * DD];     // 16 KB bf16 state copy
  __shared__ float Vp[2 * 16 * 68];             // 8.5 KB fp32 partials
  __shared__ float Up[2 * 16 * 68];             // 8.5 KB
  __shared__ __align__(16) u16 Vt[16 * 64];
  __shared__ __align__(16) u16 Ut[16 * 64];
  __shared__ __align__(16) u16 Wt[16 * 64];
  __shared__ __align__(16) u16 Ws[16 * 64];

  int b = blockIdx.x >> 6;
  int vb = blockIdx.x & 63;
  int v0 = vb * VB;
  int tid = threadIdx.x;
  int wid = tid >> 6, lane = tid & 63;
  int wq = wid & 3, kh = wid >> 2;
  int lo = lane & 15, hi = lane >> 4;
  int sidx = 16 * wq + lo;
  int mK = sx6(sidx) << 3;
  int mLo = sx6(lo) << 3;
  int kOff = kh * 256;

  float lam = 1.f / (1.f + expf(-*ll_p));
  float lam64 = powf(lam, 64.f);
  float csc = powf(lam, (float)(sidx + 1));
  float dsc = powf(lam, (float)(63 - sidx));

  {
    u32x4 z = {0u, 0u, 0u, 0u};
    *((u32x4*)Sb + tid) = z;
    *((u32x4*)Sb + 512 + tid) = z;
    if (tid < 512) {
      u16* base = (tid >> 7) == 0 ? Vt : (tid >> 7) == 1 ? Ut : (tid >> 7) == 2 ? Wt : Ws;
      *((u32x4*)base + (tid & 127)) = z;
    }
  }
  const u16* kb_b = kbs + (size_t)b * LL * DD;
  float* yb = y + (size_t)b * LL * DD;

  // W A-fragments (chunk-invariant, k-half only)
  u32x4 wf[8];
#pragma unroll
  for (int kq = 0; kq < 8; ++kq)
    wf[kq] = *(const u32x4*)(wbb + (size_t)((v0 + lo) & 511) * DD + kOff + hi * 8 + kq * 32);

  // prologue: stage chunk 0 (reg), frames for chunk 0
  u32x4 sreg[8];
#pragma unroll
  for (int i = 0; i < 8; ++i)
    sreg[i] = *(const u32x4*)(kb_b + (size_t)(i * 512 + tid) * 8);
  u32x4 kt0[4], kt1[4], tA0, tA1, tB0, tB1;
  {
    const u16* ktc = kbt + (size_t)(b * NC + 0) * CC * DD;
#pragma unroll
    for (int t = 0; t < 4; ++t) {
      int k = 16 * (8 * wq + 4 * kh + t) + lo;
      const u16* rowp = ktc + (size_t)k * 64;
      int m = sx6(k) << 3;
      kt0[t] = *(const u32x4*)(rowp + ((8 * hi) ^ m));
      kt1[t] = *(const u32x4*)(rowp + ((8 * hi + 32) ^ m));
    }
    size_t tbase = ((size_t)(b * NC + 0) * 64 + sidx) * 64 + hi * 8;
    if (kh == 0) {
      tA0 = *(const u32x4*)(tbb + tbase);
      tA1 = *(const u32x4*)(tbb + tbase + 32);
      tB0 = *(const u32x4*)(tcb + tbase);
      tB1 = *(const u32x4*)(tcb + tbase + 32);
    } else {
      tA0 = *(const u32x4*)(mtb + tbase);
      tA1 = *(const u32x4*)(mtb + tbase + 32);
      tB0 = tA0; tB1 = tA1;
    }
  }
#pragma unroll
  for (int i = 0; i < 8; ++i)
    *(u32x4*)(Kl + (size_t)(i * 512 + tid) * 8) = sreg[i];

  f32x4 Sa[4];
#pragma unroll
  for (int t = 0; t < 4; ++t) Sa[t] = (f32x4){0.f, 0.f, 0.f, 0.f};
  barrier_all();

  for (int c = 0; c < NC; ++c) {
    // issue stage loads for c+1 (land before stage-write after bar1)
    if (c + 1 < NC) {
      const u16* src = kb_b + (size_t)(c + 1) * CC * DD;
#pragma unroll
      for (int i = 0; i < 8; ++i)
        sreg[i] = *(const u32x4*)(src + (size_t)(i * 512 + tid) * 8);
    }
    // ---- phase V + A (k-half per wave) ----
    f32x4 Va0 = {0.f,0.f,0.f,0.f}, Va1 = {0.f,0.f,0.f,0.f};
    f32x4 Ua0 = {0.f,0.f,0.f,0.f}, Ua1 = {0.f,0.f,0.f,0.f};
#pragma unroll
    for (int kq = 0; kq < 8; ++kq) {
      int col = kOff + hi * 8 + kq * 32;
      bf16x8 kB = ldf(Kl + sidx * DD + (col ^ mK));
      bf16x8 sA = ldf(Sb + lo * DD + (col ^ mLo));
      if (kq & 1) {
        Va1 = __builtin_amdgcn_mfma_f32_16x16x32_bf16(bcv(wf[kq]), kB, Va1, 0, 0, 0);
        Ua1 = __builtin_amdgcn_mfma_f32_16x16x32_bf16(sA, kB, Ua1, 0, 0, 0);
      } else {
        Va0 = __builtin_amdgcn_mfma_f32_16x16x32_bf16(bcv(wf[kq]), kB, Va0, 0, 0, 0);
        Ua0 = __builtin_amdgcn_mfma_f32_16x16x32_bf16(sA, kB, Ua0, 0, 0, 0);
      }
    }
#pragma unroll
    for (int r = 0; r < 4; ++r) {
      int v = 4 * hi + r;
      Vp[(kh * 16 + v) * 68 + sidx] = Va0[r] + Va1[r];
      Up[(kh * 16 + v) * 68 + sidx] = Ua0[r] + Ua1[r];
    }
    barrier_lgkm();
    // stage-write c+1 into Kl (Kl reads for chunk c all done)
    if (c + 1 < NC) {
#pragma unroll
      for (int i = 0; i < 8; ++i)
        *(u32x4*)(Kl + (size_t)(i * 512 + tid) * 8) = sreg[i];
    }
    // ---- reduce k-halves (full V,U in regs, acc layout) ----
    float VaF[4], UaF[4];
#pragma unroll
    for (int r = 0; r < 4; ++r) {
      int v = 4 * hi + r;
      VaF[r] = Vp[v * 68 + sidx] + Vp[(16 + v) * 68 + sidx];
      UaF[r] = Up[v * 68 + sidx] + Up[(16 + v) * 68 + sidx];
    }
    if (kh == 0 && hi < 2) {
#pragma unroll
      for (int r = 0; r < 4; ++r) {
        int v = 4 * hi + r;
        int idx = v * 64 + (sidx ^ (sx6(v) << 3));
        Vt[idx] = f2bf(VaF[r]);
        Ut[idx] = f2bf(UaF[r]);
      }
    }
    barrier_lgkm();
    // ---- phase B (kh=0 waves) ----
    if (kh == 0) {
      bf16x8 vf0 = ldf(Vt + lo * 64 + ((hi * 8) ^ mLo));
      bf16x8 vf1 = ldf(Vt + lo * 64 + ((hi * 8 + 32) ^ mLo));
      bf16x8 uf0 = ldf(Ut + lo * 64 + ((hi * 8) ^ mLo));
      bf16x8 uf1 = ldf(Ut + lo * 64 + ((hi * 8 + 32) ^ mLo));
      f32x4 Wa0 = {0.f,0.f,0.f,0.f}, Wa1 = {0.f,0.f,0.f,0.f};
      Wa0 = __builtin_amdgcn_mfma_f32_16x16x32_bf16(vf0, bcv(tA0), Wa0, 0, 0, 0);
      Wa1 = __builtin_amdgcn_mfma_f32_16x16x32_bf16(vf1, bcv(tA1), Wa1, 0, 0, 0);
      Wa0 = __builtin_amdgcn_mfma_f32_16x16x32_bf16(uf0, bcv(tB0), Wa0, 0, 0, 0);
      Wa1 = __builtin_amdgcn_mfma_f32_16x16x32_bf16(uf1, bcv(tB1), Wa1, 0, 0, 0);
      f32x4 Wa = Wa0 + Wa1;
      if (hi < 2) {
#pragma unroll
        for (int r = 0; r < 4; ++r) {
          int v = 4 * hi + r;
          int idx = v * 64 + (sidx ^ (sx6(v) << 3));
          Wt[idx] = f2bf(Wa[r]);
          Ws[idx] = f2bf(Wa[r] * dsc);
        }
      }
    }
    barrier_lgkm();
    // ---- phase C (kh=1 waves) + y store ----
    if (kh == 1) {
      f32x4 Oa;
#pragma unroll
      for (int r = 0; r < 4; ++r) Oa[r] = csc * UaF[r];
      bf16x8 wff0 = ldf(Wt + lo * 64 + ((hi * 8) ^ mLo));
      bf16x8 wff1 = ldf(Wt + lo * 64 + ((hi * 8 + 32) ^ mLo));
      Oa = __builtin_amdgcn_mfma_f32_16x16x32_bf16(wff0, bcv(tA0), Oa, 0, 0, 0);
      Oa = __builtin_amdgcn_mfma_f32_16x16x32_bf16(wff1, bcv(tA1), Oa, 0, 0, 0);
      if (hi < 2) {
        float4 yo = make_float4(VaF[0] + Oa[0], VaF[1] + Oa[1],
                                VaF[2] + Oa[2], VaF[3] + Oa[3]);
        *(float4*)(yb + (size_t)(c * CC + sidx) * DD + v0 + 4 * hi) = yo;
      }
    }
    // ---- phase D (all waves, 4 tiles each) ----
    {
      bf16x8 ws0 = ldf(Ws + lo * 64 + ((hi * 8) ^ mLo));
      bf16x8 ws1 = ldf(Ws + lo * 64 + ((hi * 8 + 32) ^ mLo));
#pragma unroll
      for (int t = 0; t < 4; ++t) {
        f32x4 acc = Sa[t] * lam64;
        acc = __builtin_amdgcn_mfma_f32_16x16x32_bf16(ws0, bcv(kt0[t]), acc, 0, 0, 0);
        acc = __builtin_amdgcn_mfma_f32_16x16x32_bf16(ws1, bcv(kt1[t]), acc, 0, 0, 0);
        Sa[t] = acc;
      }
      if (hi < 2) {
#pragma unroll
        for (int t = 0; t < 4; ++t) {
          int kc = 16 * (8 * wq + 4 * kh + t) + lo;
#pragma unroll
          for (int r = 0; r < 4; ++r) {
            int v = 4 * hi + r;
            Sb[v * DD + (kc ^ (sx6(v) << 3))] = f2bf(Sa[t][r]);
          }
        }
      }
    }
    // ---- prefetch frames for c+1 (full-chunk latency cover) ----
    if (c + 1 < NC) {
      const u16* ktc = kbt + (size_t)(b * NC + c + 1) * CC * DD;
#pragma unroll
      for (int t = 0; t < 4; ++t) {
        int k = 16 * (8 * wq + 4 * kh + t) + lo;
        const u16* rowp = ktc + (size_t)k * 64;
        int m = sx6(k) << 3;
        kt0[t] = *(const u32x4*)(rowp + ((8 * hi) ^ m));
        kt1[t] = *(const u32x4*)(rowp + ((8 * hi + 32) ^ m));
      }
      size_t tbase = ((size_t)(b * NC + c + 1) * 64 + sidx) * 64 + hi * 8;
      if (kh == 0) {
        tA0 = *(const u32x4*)(tbb + tbase);
        tA1 = *(const u32x4*)(tbb + tbase + 32);
        tB0 = *(const u32x4*)(tcb + tbase);
        tB1 = *(const u32x4*)(tcb + tbase + 32);
      } else {
        tA0 = *(const u32x4*)(mtb + tbase);
        tA1 = *(const u32x4*)(mtb + tbase + 32);
      }
    }
    barrier_lgkm();
  }
}

// ---------------------------------------------------------------------------
// K4: LayerNorm in-place on d_out.
// ---------------------------------------------------------------------------
__global__ __launch_bounds__(256) void k_ln(float* __restrict__ y,
                                            const float* __restrict__ gamma,
                                            const float* __restrict__ lbeta) {
  int row = blockIdx.x * 4 + (threadIdx.x >> 6);
  int lane = threadIdx.x & 63;
  float* yr = y + (size_t)row * DD + lane * 8;
  float4 a = *(const float4*)yr;
  float4 b = *(const float4*)(yr + 4);
  float v[8] = {a.x, a.y, a.z, a.w, b.x, b.y, b.z, b.w};
  float s = 0.f, ss = 0.f;
#pragma unroll
  for (int j = 0; j < 8; ++j) {
    s += v[j];
    ss = fmaf(v[j], v[j], ss);
  }
#pragma unroll
  for (int m = 1; m < 64; m <<= 1) {
    s += __shfl_xor(s, m, 64);
    ss += __shfl_xor(ss, m, 64);
  }
  float mu = s * (1.f / DD);
  float var = ss * (1.f / DD) - mu * mu;
  float inv = rsqrtf(var + EPSF);
  const float* gp = gamma + lane * 8;
  const float* bp = lbeta + lane * 8;
  float4 g0 = *(const float4*)gp;
  float4 g1 = *(const float4*)(gp + 4);
  float4 b0 = *(const float4*)bp;
  float4 b1 = *(const float4*)(bp + 4);
  float g[8] = {g0.x, g0.y, g0.z, g0.w, g1.x, g1.y, g1.z, g1.w};
  float bb[8] = {b0.x, b0.y, b0.z, b0.w, b1.x, b1.y, b1.z, b1.w};
#pragma unroll
  for (int j = 0; j < 8; ++j) v[j] = (v[j] - mu) * inv * g[j] + bb[j];
  *(float4*)yr = make_float4(v[0], v[1], v[2], v[3]);
  *(float4*)(yr + 4) = make_float4(v[4], v[5], v[6], v[7]);
}

// ---------------------------------------------------------------------------
extern "C" void kernel_launch(void* const* d_in, const int* in_sizes, int n_in,
                              void* d_out, int out_size, void* d_ws, size_t ws_size,
                              hipStream_t stream) {
  const float* x     = (const float*)d_in[0];
  const float* W     = (const float*)d_in[1];
  const float* eta   = (const float*)d_in[2];
  const float* ll    = (const float*)d_in[3];
  const float* gamma = (const float*)d_in[4];
  const float* lbeta = (const float*)d_in[5];
  float* out = (float*)d_out;

  // ws (u16): kbs 8MB | kbt 8MB | wbb 0.5MB | tbb/tcb/mtb 1MB each (~20.5MB)
  u16* kbs = (u16*)d_ws;
  u16* kbt = kbs + (size_t)BB * LL * DD;
  u16* wbb = kbt + (size_t)BB * LL * DD;
  u16* tbb = wbb + (size_t)DD * DD;
  u16* tcb = tbb + (size_t)BB * NC * 64 * 64;
  u16* mtb = tcb + (size_t)BB * NC * 64 * 64;

  k_tanh<<<2048, 256, 0, stream>>>(x, kbs);
  k_cvtW<<<128, 256, 0, stream>>>(W, wbb);
  k_prep2<<<BB * NC, 256, 0, stream>>>(kbs, eta, ll, tbb, tcb, mtb, kbt);
  k_scan6<<<256, 512, 0, stream>>>(kbs, kbt, wbb, tbb, tcb, mtb, ll, out);
  k_ln<<<2048, 256, 0, stream>>>(out, gamma, lbeta);
}